// Round 5
// baseline (1158.325 us; speedup 1.0000x reference)
//
#include <hip/hip_runtime.h>
#include <hip/hip_bf16.h>

typedef __hip_bfloat16 bf16_t;

static const int cT  = 12;    // future steps
static const int cN  = 128;   // agents
static const int cH  = 128;   // hidden
static const int cK  = 20;    // modes
static const int cKN = 2560;  // cK*cN
static const int cS  = 4;     // batch split
static const int cNS = 32;    // agents per scene
static const int cL  = 640;   // cK*cNS attention length
static const int cHD = 32;    // head dim

#define CONV_TOTAL 977986

__constant__ int c_off[38] = {0,196608,212992,229376,229632,229888,557568,560128,562688,
  565248,630784,696320,696832,762368,827904,828416,844800,844928,861312,861440,877824,
  877952,910720,910976,943744,943872,960256,960384,960512,960640,960896,960960,977344,
  977472,977600,977728,977984,977986};
__constant__ int c_len[37] = {196608,16384,16384,256,256,327680,2560,2560,2560,
  65536,65536,512,65536,65536,512,16384,128,16384,128,16384,128,
  32768,256,32768,128,16384,128,128,128,256,2,16384,128,128,128,256,2};

struct Ptrs { const void* p[37]; };

typedef __attribute__((ext_vector_type(4))) float f32x4;
typedef __attribute__((ext_vector_type(8))) __bf16 bf16x8;

__device__ __forceinline__ float sigm(float x){ return 1.f/(1.f+expf(-x)); }
__device__ __forceinline__ unsigned short f2h(float x){ return (unsigned short)(__float_as_uint(x)>>16); }
__device__ __forceinline__ float hif(float x){ return __uint_as_float(__float_as_uint(x)&0xFFFF0000u); }

// dtype sniffing + NaN canary
__global__ __launch_bounds__(256) void k_detect(const unsigned short* ge_u16, int* flagp, unsigned int* outw){
  __shared__ int cnt;
  if (threadIdx.x == 0) cnt = 0;
  __syncthreads();
  int ok = 0;
  for (int i = threadIdx.x; i < 128; i += 64){
    unsigned short u = ge_u16[2*i];
    int ex = (u >> 7) & 0xFF;
    if (ex >= 100 && ex <= 140) ok++;
  }
  atomicAdd(&cnt, ok);
  __syncthreads();
  if (threadIdx.x == 0){
    *flagp = (cnt >= 96) ? 1 : 0;
    outw[0] = 0x7FC07FC0u;
  }
}

// convert all 37 inputs to fp32 into the conv region
__global__ __launch_bounds__(256) void k_convert(Ptrs ptrs, const int* flagp, float* dst){
  int g = blockIdx.x*256 + threadIdx.x;
  if (g >= CONV_TOTAL) return;
  int flag = *flagp;
  int seg = 0;
  while (seg < 36 && g >= c_off[seg+1]) ++seg;
  int local = g - c_off[seg];
  if (local >= c_len[seg]) return;
  float v;
  if (flag) v = __bfloat162float(((const bf16_t*)ptrs.p[seg])[local]);
  else      v = ((const float*)ptrs.p[seg])[local];
  dst[g] = v;
}

// ge = relu(LN_2560(x @ mhp_W + b)), 2 rows per block, weight reuse across rows
__global__ __launch_bounds__(256) void k_mhp(const float* x, const float* W, const float* b,
                      const float* g, const float* be, float* out){
  const int ROWS = 2;
  int r0 = blockIdx.x*ROWS;
  __shared__ float xs[ROWS][cH];
  __shared__ float red[256][3];
  int tid = threadIdx.x;
  if (tid < ROWS*32){
    int rr = tid>>5, u4 = tid&31;
    ((float4*)&xs[rr][0])[u4] = ((const float4*)x)[(r0+rr)*32 + u4];
  }
  __syncthreads();
  float y[ROWS][10];
  #pragma unroll
  for (int m = 0; m < 10; ++m){ float bb = b[tid + 256*m]; y[0][m] = bb; y[1][m] = bb; }
  for (int i = 0; i < cH; ++i){
    float x0 = xs[0][i], x1 = xs[1][i];
    const float* wr = W + i*2560 + tid;
    #pragma unroll
    for (int m = 0; m < 10; ++m){
      float w = wr[256*m];
      y[0][m] += x0*w; y[1][m] += x1*w;
    }
  }
  float ps0 = 0.f, ps1 = 0.f;
  #pragma unroll
  for (int m = 0; m < 10; ++m){ ps0 += y[0][m]; ps1 += y[1][m]; }
  red[tid][0] = ps0; red[tid][1] = ps1; __syncthreads();
  for (int s2 = 128; s2 > 0; s2 >>= 1){
    if (tid < s2){ red[tid][0] += red[tid+s2][0]; red[tid][1] += red[tid+s2][1]; }
    __syncthreads();
  }
  float mean0 = red[0][0]*(1.f/2560.f), mean1 = red[0][1]*(1.f/2560.f);
  __syncthreads();
  float pv0 = 0.f, pv1 = 0.f;
  #pragma unroll
  for (int m = 0; m < 10; ++m){
    float d0 = y[0][m]-mean0, d1 = y[1][m]-mean1;
    pv0 += d0*d0; pv1 += d1*d1;
  }
  red[tid][0] = pv0; red[tid][1] = pv1; __syncthreads();
  for (int s2 = 128; s2 > 0; s2 >>= 1){
    if (tid < s2){ red[tid][0] += red[tid+s2][0]; red[tid][1] += red[tid+s2][1]; }
    __syncthreads();
  }
  float inv0 = rsqrtf(red[0][0]*(1.f/2560.f) + 1e-5f);
  float inv1 = rsqrtf(red[0][1]*(1.f/2560.f) + 1e-5f);
  #pragma unroll
  for (int rr = 0; rr < ROWS; ++rr){
    int rg = r0 + rr;
    int t = rg >> 7, nn = rg & 127;
    float mean = rr ? mean1 : mean0;
    float inv  = rr ? inv1  : inv0;
    #pragma unroll
    for (int m = 0; m < 10; ++m){
      int col = tid + 256*m;
      float z = (y[rr][m]-mean)*inv*g[col] + be[col];
      z = fmaxf(z, 0.f);
      int k = col >> 7, hh2 = col & 127;
      out[((t*cKN) + k*cN + nn)*cH + hh2] = z;
    }
  }
}

// fused 12-step LSTM, round-11: ROWS 8 -> 4 (grid 320 -> 640 blocks).
// R4 counters: Occupancy 12.3% (1.25 blocks/CU = 1 wave/SIMD), VALUBusy 37%,
// HBM 1.2% -> latency-bound with zero TLP. ROWS=4 doubles waves/CU to 10
// (2.5/SIMD); unique L2 weight traffic doubles to ~3.9 GB (~22 TB/s at the
// projected 180 us) - still under the 34.5 TB/s L2 ceiling. ROWS=2 would
// exceed it (52 TB/s), so 4 is the sweet spot.
__global__ __launch_bounds__(256) void k_lstm_seq(const float* ge, float* outh,
    const float* hs0, const float* cn0, const float* soc,
    const float* Wih, const float* Whh, const float* bias, int phase){
  const int ROWS = 4;
  int r0 = blockIdx.x * ROWS;
  __shared__ float xs[ROWS][cH], hs[ROWS][cH], cs[ROWS][cH];
  int tid = threadIdx.x;
  {
    int rr = tid>>6, u2 = tid&63;
    int nn = (r0+rr) & 127;
    ((float2*)&hs[rr][0])[u2] = ((const float2*)hs0)[nn*64 + u2];
    ((float2*)&cs[rr][0])[u2] = ((const float2*)cn0)[nn*64 + u2];
  }
  int u = tid & 127, half = tid >> 7;
  float b0 = bias[u], b1 = bias[128+u], b2 = bias[256+u], b3 = bias[384+u];
  for (int t = 0; t < cT; ++t){
    __syncthreads();   // orders previous step's hs/cs gate-writes vs this RMW
    {
      int rr = tid>>6, u2 = tid&63;
      size_t gi2 = (size_t)t*cKN*64 + (size_t)(r0+rr)*64 + u2;
      ((float2*)&xs[rr][0])[u2] = ((const float2*)ge)[gi2];
      if (phase == 2){
        float2 sv = ((const float2*)soc)[gi2];
        float2 cv = ((float2*)&cs[rr][0])[u2];
        float2 hv = ((float2*)&hs[rr][0])[u2];
        cv.x += sv.x; cv.y += sv.y;
        hv.x += tanhf(cv.x); hv.y += tanhf(cv.y);
        ((float2*)&cs[rr][0])[u2] = cv;
        ((float2*)&hs[rr][0])[u2] = hv;
      }
    }
    __syncthreads();
    float a[2][4] = {{0,0,0,0},{0,0,0,0}};
    for (int i = 0; i < cH; ++i){
      const float* wr = Wih + i*512 + u;
      const float* vr = Whh + i*512 + u;
      float w0 = wr[0], w1 = wr[128], w2 = wr[256], w3 = wr[384];
      float v0 = vr[0], v1 = vr[128], v2 = vr[256], v3 = vr[384];
      #pragma unroll
      for (int q = 0; q < 2; ++q){
        int rr = half + 2*q;
        float xi = xs[rr][i], hi = hs[rr][i];
        a[q][0] += xi*w0 + hi*v0;
        a[q][1] += xi*w1 + hi*v1;
        a[q][2] += xi*w2 + hi*v2;
        a[q][3] += xi*w3 + hi*v3;
      }
    }
    __syncthreads();   // all dot reads of hs/cs done before overwrite
    #pragma unroll
    for (int q = 0; q < 2; ++q){
      int rr = half + 2*q;
      float ig = sigm(a[q][0]+b0), fg = sigm(a[q][1]+b1);
      float gg = tanhf(a[q][2]+b2), og = sigm(a[q][3]+b3);
      float c2 = fg*cs[rr][u] + ig*gg;
      float h2 = og*tanhf(c2);
      cs[rr][u] = c2; hs[rr][u] = h2;
      outh[(size_t)t*cKN*cH + (size_t)(r0+rr)*cH + u] = h2;
    }
  }
}

// loc & scale heads, wave-local: wave = (head, row-pair), shfl reductions, no trees.
__global__ __launch_bounds__(256) void k_heads(const float* x,
  const float* lW1, const float* lb1, const float* lg, const float* lbe, const float* lW2, const float* lb2v,
  const float* sW1, const float* sb1, const float* sg, const float* sbe, const float* sW2, const float* sb2v,
  void* outv, int q0, float* locsc, const float* maxv, const float* svp, const int* flagp){
  const int ROWS = 4;
  int r0 = blockIdx.x*ROWS;
  __shared__ float xs[ROWS][cH];
  int tid = threadIdx.x;
  if (tid < ROWS*32){
    int rr = tid>>5, u4 = tid&31;
    ((float4*)&xs[rr][0])[u4] = ((const float4*)x)[(size_t)(r0+rr)*32 + u4];
  }
  __syncthreads();
  int wv = tid >> 6, lane = tid & 63;
  int head = wv & 1;
  int ra = (wv >> 1)*2, rb = ra + 1;     // local rows
  const float* W1 = head ? sW1 : lW1;
  const float* b1 = head ? sb1 : lb1;
  const float* gv = head ? sg  : lg;
  const float* be = head ? sbe : lbe;
  const float* W2 = head ? sW2 : lW2;
  const float* b2 = head ? sb2v: lb2v;
  int j0 = lane, j1 = lane + 64;
  float a00 = b1[j0], a01 = b1[j1];
  float a10 = a00, a11 = a01;
  for (int i = 0; i < cH; ++i){
    float w0 = W1[i*cH + j0], w1 = W1[i*cH + j1];
    float xa = xs[ra][i], xb = xs[rb][i];
    a00 += xa*w0; a01 += xa*w1;
    a10 += xb*w0; a11 += xb*w1;
  }
  float s0 = a00 + a01, s1 = a10 + a11;
  #pragma unroll
  for (int off = 1; off < 64; off <<= 1){
    s0 += __shfl_xor(s0, off);
    s1 += __shfl_xor(s1, off);
  }
  float mean0 = s0*(1.f/128.f), mean1 = s1*(1.f/128.f);
  float d00 = a00-mean0, d01 = a01-mean0, d10 = a10-mean1, d11 = a11-mean1;
  float v0 = d00*d00 + d01*d01, v1 = d10*d10 + d11*d11;
  #pragma unroll
  for (int off = 1; off < 64; off <<= 1){
    v0 += __shfl_xor(v0, off);
    v1 += __shfl_xor(v1, off);
  }
  float inv0 = rsqrtf(v0*(1.f/128.f) + 1e-5f);
  float inv1 = rsqrtf(v1*(1.f/128.f) + 1e-5f);
  float g0 = gv[j0], g1 = gv[j1], be0 = be[j0], be1 = be[j1];
  float z00 = fmaxf(d00*inv0*g0 + be0, 0.f);
  float z01 = fmaxf(d01*inv0*g1 + be1, 0.f);
  float z10 = fmaxf(d10*inv1*g0 + be0, 0.f);
  float z11 = fmaxf(d11*inv1*g1 + be1, 0.f);
  float w2a0 = W2[j0*2+0], w2a1 = W2[j0*2+1];
  float w2b0 = W2[j1*2+0], w2b1 = W2[j1*2+1];
  float oa0 = z00*w2a0 + z01*w2b0;   // row ra, out 0
  float oa1 = z00*w2a1 + z01*w2b1;   // row ra, out 1
  float ob0 = z10*w2a0 + z11*w2b0;
  float ob1 = z10*w2a1 + z11*w2b1;
  #pragma unroll
  for (int off = 1; off < 64; off <<= 1){
    oa0 += __shfl_xor(oa0, off);
    oa1 += __shfl_xor(oa1, off);
    ob0 += __shfl_xor(ob0, off);
    ob1 += __shfl_xor(ob1, off);
  }
  if (lane == 0){
    int flag = *flagp;
    float bias0 = b2[0], bias1 = b2[1];
    float ro[2][2] = {{oa0 + bias0, oa1 + bias1},{ob0 + bias0, ob1 + bias1}};
    int lr[2] = {ra, rb};
    for (int e = 0; e < 2; ++e){
      int rg = r0 + lr[e];
      int t = rg / cKN, rem = rg - t*cKN;
      int k = rem >> 7, nn = rem & 127;
      float u0 = ro[e][0], u1 = ro[e][1];
      if (head == 0){
        size_t oi = (((size_t)q0*cK + k)*cN + nn)*(cT*2) + t*2;
        if (flag){ ((bf16_t*)outv)[oi] = __float2bfloat16(u0); ((bf16_t*)outv)[oi+1] = __float2bfloat16(u1); }
        else     { ((float*)outv)[oi] = u0; ((float*)outv)[oi+1] = u1; }
        if (locsc){
          locsc[((size_t)t*cKN + rem)*2 + 0] = u0*maxv[nn*2+0] + svp[nn*2+0];
          locsc[((size_t)t*cKN + rem)*2 + 1] = u1*maxv[nn*2+1] + svp[nn*2+1];
        }
      } else {
        float e0 = (u0 > 0.f ? u0 : expm1f(u0)) + 1.001f;
        float e1 = (u1 > 0.f ? u1 : expm1f(u1)) + 1.001f;
        size_t oi = (((size_t)(q0+1)*cK + k)*cN + nn)*(cT*2) + t*2;
        if (flag){ ((bf16_t*)outv)[oi] = __float2bfloat16(e0); ((bf16_t*)outv)[oi+1] = __float2bfloat16(e1); }
        else     { ((float*)outv)[oi] = e0; ((float*)outv)[oi+1] = e1; }
      }
    }
  }
}

__global__ __launch_bounds__(256) void k_mask(const float* locsc, unsigned char* m){
  int st = blockIdx.x;
  int s = st / cT, t = st - s*cT;
  __shared__ float lx[cK][cNS], ly[cK][cNS];
  int tid = threadIdx.x;
  for (int p = tid; p < cK*cNS; p += 256){
    int k = p >> 5, i = p & 31;
    int row = t*cKN + k*cN + s*cNS + i;
    lx[k][i] = locsc[row*2+0];
    ly[k][i] = locsc[row*2+1];
  }
  __syncthreads();
  for (int p = tid; p < 1024; p += 256){
    int i = p >> 5, j = p & 31;
    bool any = false;
    for (int k = 0; k < cK; ++k){
      float dx = fabsf(lx[k][i]-lx[k][j]);
      float dy = fabsf(ly[k][i]-ly[k][j]);
      any = any || ((dx < 10.f) && (dy < 10.f));
    }
    m[st*1024 + p] = any ? 1 : 0;
  }
}

// QKV projection, 16 rows/block, weight reuse for 8 rows/thread
__global__ __launch_bounds__(256) void k_qkv(const float* x,
  const float* Wq, const float* bq, const float* Wk, const float* bk,
  const float* Wv, const float* bv,
  float* Q, float* K2, float* V){
  const int ROWS = 16;
  int r0 = blockIdx.x*ROWS;
  __shared__ float xs[ROWS][cH];
  int tid = threadIdx.x;
  for (int p = tid; p < ROWS*32; p += 256){
    int rr = p>>5, u4 = p&31;
    ((float4*)&xs[rr][0])[u4] = ((const float4*)x)[(size_t)(r0+rr)*32 + u4];
  }
  __syncthreads();
  int cl = tid & 127, half = tid >> 7;
  float aq[8], ak[8], av[8];
  float bq0 = bq[cl], bk0 = bk[cl], bv0 = bv[cl];
  #pragma unroll
  for (int r = 0; r < 8; ++r){ aq[r] = bq0; ak[r] = bk0; av[r] = bv0; }
  for (int i = 0; i < cH; ++i){
    float wq = Wq[i*cH+cl], wk = Wk[i*cH+cl], wv = Wv[i*cH+cl];
    #pragma unroll
    for (int q2 = 0; q2 < 8; ++q2){
      float xi = xs[half + 2*q2][i];
      aq[q2] += xi*wq; ak[q2] += xi*wk; av[q2] += xi*wv;
    }
  }
  #pragma unroll
  for (int q2 = 0; q2 < 8; ++q2){
    size_t gi = (size_t)(r0 + half + 2*q2)*cH + cl;
    Q[gi] = aq[q2]; K2[gi] = ak[q2]; V[gi] = av[q2];
  }
}

// round-10: MFMA attention. Split-bf16 (hi+lo) 3-mfma products give fp32-level
// accuracy; QK^T = mfma(A=K, B=Q) => D[key][q]; with k-map
// k = 16*(e>>2)+4g+(e&3) the PV A-fragment (P^T) is exactly the lane's own
// S-accumulator registers (zero shuffles / zero P LDS). K/V staged to LDS
// pre-arranged in fragment order (b64 packed bf16 hi/lo). A consistent k-map
// permutation between A and B cancels in the contraction, so only the
// HW-verified row/col = lane&15 and D-layout mappings are load-bearing.
// No-max softmax (verified R3). 8 b128 frag reads/wave/chunk vs 800/thread before.
__global__ __launch_bounds__(256) void k_attn(const float* Q, const float* Kx, const float* V,
                       const unsigned char* msk, float* ctx){
  int qs   = blockIdx.x;        // 0..4 : group of 8 q-tiles (2 per wave)
  int head = blockIdx.y;        // 0..3
  int st   = blockIdx.z;        // s*cT + t
  int s = st / cT, t = st - s*cT;
  __shared__ unsigned short KLh[2][1024], KLl[2][1024], VLh[2][1024], VLl[2][1024]; // 16 KB
  int tid = threadIdx.x;
  int w = tid >> 6, lane = tid & 63;
  int g = lane >> 4, col = lane & 15;
  const float scl = 0.17677669529663687f;   // 1/sqrt(32)

  // mask rows (q_agent = col, col+16) packed to 32-bit words (byte->bit)
  unsigned int mw0 = 0, mw1 = 0;
  {
    const unsigned int* mr0 = (const unsigned int*)(msk + st*1024 + col*32);
    const unsigned int* mr1 = (const unsigned int*)(msk + st*1024 + (16+col)*32);
    #pragma unroll
    for (int j2 = 0; j2 < 8; ++j2){
      mw0 |= (((mr0[j2] * 0x01020408u) >> 24) & 0xFu) << (4*j2);
      mw1 |= (((mr1[j2] * 0x01020408u) >> 24) & 0xFu) << (4*j2);
    }
  }

  // Q fragments (pre-scaled by scl), 2 tiles per wave; B col = lane&15
  bf16x8 Qh[2], Ql[2];
  int modes[2], ahs[2];
  #pragma unroll
  for (int i = 0; i < 2; ++i){
    int tt = qs*8 + 4*i + w;       // 0..39
    int mode = tt >> 1, ah = tt & 1;
    modes[i] = mode; ahs[i] = ah;
    int qrow = t*cKN + mode*cN + s*cNS + ah*16 + col;
    const f32x4* qp = (const f32x4*)Q + (size_t)qrow*32 + head*8;
    f32x4 qa = qp[g], qb = qp[4+g];     // dims 4g..4g+3, 16+4g..16+4g+3
    union { unsigned short u[8]; bf16x8 v; } uh, ul;
    #pragma unroll
    for (int m = 0; m < 4; ++m){
      float x0 = qa[m]*scl;
      uh.u[m] = f2h(x0);
      ul.u[m] = f2h(x0 - hif(x0));
      float x1 = qb[m]*scl;
      uh.u[4+m] = f2h(x1);
      ul.u[4+m] = f2h(x1 - hif(x1));
    }
    Qh[i] = uh.v; Ql[i] = ul.v;
  }

  // staging indices
  int kk = tid >> 3, f4 = tid & 7;                 // K: key kk, dims 4*f4..+3
  int kwi = (((kk>>4)*4 + (f4&3))*16 + (kk&15))*8 + (f4>>2)*4;
  int vd = tid & 31, quad = tid >> 5;              // V: dim vd, keys base..+3
  int vkey = (quad>>2)*16 + (quad&3)*4;
  int vwi = (((vd>>4)*4 + (quad&3))*16 + (vd&15))*8 + (quad>>2)*4;

  const size_t cstepK = (size_t)cN*32;             // float4 per chunk (one mode)
  const size_t cstepV = (size_t)cN*128;            // float per chunk
  const float4* kptr = (const float4*)Kx + ((size_t)(t*cKN + s*cNS + kk))*32 + head*8 + f4;
  const float*  vptr = V + ((size_t)(t*cKN + s*cNS + vkey))*128 + head*32 + vd;

  float4 kv; float vm0, vm1, vm2, vm3;
  kv = *kptr; kptr += cstepK;
  vm0 = vptr[0]; vm1 = vptr[128]; vm2 = vptr[256]; vm3 = vptr[384]; vptr += cstepV;
  {
    unsigned int h0 = (unsigned int)f2h(kv.x) | ((unsigned int)f2h(kv.y)<<16);
    unsigned int h1 = (unsigned int)f2h(kv.z) | ((unsigned int)f2h(kv.w)<<16);
    float r0 = kv.x-hif(kv.x), r1 = kv.y-hif(kv.y), r2 = kv.z-hif(kv.z), r3 = kv.w-hif(kv.w);
    unsigned int l0 = (unsigned int)f2h(r0) | ((unsigned int)f2h(r1)<<16);
    unsigned int l1 = (unsigned int)f2h(r2) | ((unsigned int)f2h(r3)<<16);
    *(uint2*)&KLh[0][kwi] = make_uint2(h0,h1);
    *(uint2*)&KLl[0][kwi] = make_uint2(l0,l1);
    unsigned int vh0 = (unsigned int)f2h(vm0) | ((unsigned int)f2h(vm1)<<16);
    unsigned int vh1 = (unsigned int)f2h(vm2) | ((unsigned int)f2h(vm3)<<16);
    float s0 = vm0-hif(vm0), s1 = vm1-hif(vm1), s2 = vm2-hif(vm2), s3 = vm3-hif(vm3);
    unsigned int vl0 = (unsigned int)f2h(s0) | ((unsigned int)f2h(s1)<<16);
    unsigned int vl1 = (unsigned int)f2h(s2) | ((unsigned int)f2h(s3)<<16);
    *(uint2*)&VLh[0][vwi] = make_uint2(vh0,vh1);
    *(uint2*)&VLl[0][vwi] = make_uint2(vl0,vl1);
  }
  __syncthreads();

  const f32x4 Z = {0.f, 0.f, 0.f, 0.f};
  f32x4 O[2][2] = {{Z, Z}, {Z, Z}};
  float lac[2] = {0.f, 0.f};

  for (int ch = 0; ch < 20; ++ch){
    int par = ch & 1;
    if (ch < 19){
      kv = *kptr; kptr += cstepK;
      vm0 = vptr[0]; vm1 = vptr[128]; vm2 = vptr[256]; vm3 = vptr[384]; vptr += cstepV;
    }
    // fragment reads (shared across this wave's tiles)
    bf16x8 KAh0 = *(const bf16x8*)&KLh[par][( g      *16 + col)*8];
    bf16x8 KAl0 = *(const bf16x8*)&KLl[par][( g      *16 + col)*8];
    bf16x8 KAh1 = *(const bf16x8*)&KLh[par][((4 + g) *16 + col)*8];
    bf16x8 KAl1 = *(const bf16x8*)&KLl[par][((4 + g) *16 + col)*8];
    bf16x8 VBh0 = *(const bf16x8*)&VLh[par][( g      *16 + col)*8];
    bf16x8 VBl0 = *(const bf16x8*)&VLl[par][( g      *16 + col)*8];
    bf16x8 VBh1 = *(const bf16x8*)&VLh[par][((4 + g) *16 + col)*8];
    bf16x8 VBl1 = *(const bf16x8*)&VLl[par][((4 + g) *16 + col)*8];
    #pragma unroll
    for (int i = 0; i < 2; ++i){
      f32x4 sa = Z, sb = Z;
      sa = __builtin_amdgcn_mfma_f32_16x16x32_bf16(KAl0, Qh[i], sa, 0, 0, 0);
      sa = __builtin_amdgcn_mfma_f32_16x16x32_bf16(KAh0, Ql[i], sa, 0, 0, 0);
      sa = __builtin_amdgcn_mfma_f32_16x16x32_bf16(KAh0, Qh[i], sa, 0, 0, 0);
      sb = __builtin_amdgcn_mfma_f32_16x16x32_bf16(KAl1, Qh[i], sb, 0, 0, 0);
      sb = __builtin_amdgcn_mfma_f32_16x16x32_bf16(KAh1, Ql[i], sb, 0, 0, 0);
      sb = __builtin_amdgcn_mfma_f32_16x16x32_bf16(KAh1, Qh[i], sb, 0, 0, 0);
      unsigned int mw = ahs[i] ? mw1 : mw0;
      float p[8];
      #pragma unroll
      for (int r = 0; r < 4; ++r){
        float e0 = __expf(sa[r]);
        float e1 = __expf(sb[r]);
        p[r]   = ((mw >> (4*g + r)) & 1)        ? e0 : 0.f;
        p[4+r] = ((mw >> (16 + 4*g + r)) & 1)   ? e1 : 0.f;
      }
      lac[i] += ((p[0]+p[1])+(p[2]+p[3])) + ((p[4]+p[5])+(p[6]+p[7]));
      union { unsigned short u[8]; bf16x8 v; } Ph, Pl;
      #pragma unroll
      for (int e = 0; e < 8; ++e){
        Ph.u[e] = f2h(p[e]);
        Pl.u[e] = f2h(p[e] - hif(p[e]));
      }
      O[i][0] = __builtin_amdgcn_mfma_f32_16x16x32_bf16(Pl.v, VBh0, O[i][0], 0, 0, 0);
      O[i][0] = __builtin_amdgcn_mfma_f32_16x16x32_bf16(Ph.v, VBl0, O[i][0], 0, 0, 0);
      O[i][0] = __builtin_amdgcn_mfma_f32_16x16x32_bf16(Ph.v, VBh0, O[i][0], 0, 0, 0);
      O[i][1] = __builtin_amdgcn_mfma_f32_16x16x32_bf16(Pl.v, VBh1, O[i][1], 0, 0, 0);
      O[i][1] = __builtin_amdgcn_mfma_f32_16x16x32_bf16(Ph.v, VBl1, O[i][1], 0, 0, 0);
      O[i][1] = __builtin_amdgcn_mfma_f32_16x16x32_bf16(Ph.v, VBh1, O[i][1], 0, 0, 0);
    }
    __syncthreads();   // all frag reads of [par] done
    if (ch < 19){
      int nb = 1 - par;
      unsigned int h0 = (unsigned int)f2h(kv.x) | ((unsigned int)f2h(kv.y)<<16);
      unsigned int h1 = (unsigned int)f2h(kv.z) | ((unsigned int)f2h(kv.w)<<16);
      float r0 = kv.x-hif(kv.x), r1 = kv.y-hif(kv.y), r2 = kv.z-hif(kv.z), r3 = kv.w-hif(kv.w);
      unsigned int l0 = (unsigned int)f2h(r0) | ((unsigned int)f2h(r1)<<16);
      unsigned int l1 = (unsigned int)f2h(r2) | ((unsigned int)f2h(r3)<<16);
      *(uint2*)&KLh[nb][kwi] = make_uint2(h0,h1);
      *(uint2*)&KLl[nb][kwi] = make_uint2(l0,l1);
      unsigned int vh0 = (unsigned int)f2h(vm0) | ((unsigned int)f2h(vm1)<<16);
      unsigned int vh1 = (unsigned int)f2h(vm2) | ((unsigned int)f2h(vm3)<<16);
      float s0 = vm0-hif(vm0), s1 = vm1-hif(vm1), s2 = vm2-hif(vm2), s3 = vm3-hif(vm3);
      unsigned int vl0 = (unsigned int)f2h(s0) | ((unsigned int)f2h(s1)<<16);
      unsigned int vl1 = (unsigned int)f2h(s2) | ((unsigned int)f2h(s3)<<16);
      *(uint2*)&VLh[nb][vwi] = make_uint2(vh0,vh1);
      *(uint2*)&VLl[nb][vwi] = make_uint2(vl0,vl1);
    }
    __syncthreads();   // next buffer visible
  }

  // epilogue: row denominators + normalized writes
  #pragma unroll
  for (int i = 0; i < 2; ++i){
    float lsum = lac[i];
    lsum += __shfl_xor(lsum, 16);
    lsum += __shfl_xor(lsum, 32);
    int base = t*cKN + modes[i]*cN + s*cNS + ahs[i]*16;
    #pragma unroll
    for (int r = 0; r < 4; ++r){
      float lq = __shfl(lsum, 4*g + r);
      float rinv = 1.f / lq;
      float* cp = ctx + (size_t)(base + 4*g + r)*cH + head*cHD;
      cp[col]      = O[i][0][r] * rinv;
      cp[col+16]   = O[i][1][r] * rinv;
    }
  }
}

// Wo1 + relu, 8 rows/block, weight reuse
__global__ __launch_bounds__(256) void k_wo1(const float* x, const float* W, const float* b, float* o){
  const int ROWS = 8;
  int r0 = blockIdx.x*ROWS;
  __shared__ float xs[ROWS][cH];
  int tid = threadIdx.x;
  {
    int rr = tid>>5, u4 = tid&31;
    ((float4*)&xs[rr][0])[u4] = ((const float4*)x)[(size_t)(r0+rr)*32 + u4];
  }
  __syncthreads();
  float a[8];
  float bb = b[tid];
  #pragma unroll
  for (int r = 0; r < 8; ++r) a[r] = bb;
  for (int i = 0; i < cH; ++i){
    float w = W[i*256 + tid];
    #pragma unroll
    for (int r = 0; r < 8; ++r) a[r] += xs[r][i]*w;
  }
  #pragma unroll
  for (int r = 0; r < 8; ++r) o[(size_t)(r0+r)*256 + tid] = fmaxf(a[r], 0.f);
}

// Wo2, 16 rows/block, weight reuse
__global__ __launch_bounds__(256) void k_wo2(const float* x, const float* W, const float* b, float* o){
  const int ROWS = 16;
  int r0 = blockIdx.x*ROWS;
  __shared__ float xs[ROWS][256];
  int tid = threadIdx.x;
  for (int p = tid; p < ROWS*64; p += 256){
    int rr = p>>6, u4 = p&63;
    ((float4*)&xs[rr][0])[u4] = ((const float4*)x)[(size_t)(r0+rr)*64 + u4];
  }
  __syncthreads();
  int cl = tid & 127, half = tid >> 7;
  float a[8];
  float bb = b[cl];
  #pragma unroll
  for (int r = 0; r < 8; ++r) a[r] = bb;
  for (int i = 0; i < 256; ++i){
    float w = W[i*cH + cl];
    #pragma unroll
    for (int q2 = 0; q2 < 8; ++q2) a[q2] += xs[half + 2*q2][i]*w;
  }
  #pragma unroll
  for (int q2 = 0; q2 < 8; ++q2) o[(size_t)(r0 + half + 2*q2)*cH + cl] = a[q2];
}

extern "C" void kernel_launch(void* const* d_in, const int* in_sizes, int n_in,
                              void* d_out, int out_size, void* d_ws, size_t ws_size,
                              hipStream_t stream){
  (void)in_sizes; (void)n_in; (void)out_size; (void)ws_size;

  int*   flagp = (int*)d_ws;
  float* conv  = (float*)d_ws + 64;
  float* big   = (float*)d_ws + 978112;

  const float* ge_f   = conv + 0;
  const float* hs_f   = conv + 196608;
  const float* cn_f   = conv + 212992;
  const float* sv_f   = conv + 229376;
  const float* mx_f   = conv + 229632;
  const float* mhpW_f = conv + 229888;
  const float* mhpb_f = conv + 557568;
  const float* mhpg_f = conv + 560128;
  const float* mhpbe_f= conv + 562688;
  const float* l1Wih_f= conv + 565248;
  const float* l1Whh_f= conv + 630784;
  const float* l1b_f  = conv + 696320;
  const float* l2Wih_f= conv + 696832;
  const float* l2Whh_f= conv + 762368;
  const float* l2b_f  = conv + 827904;
  const float* Wq_f   = conv + 828416;
  const float* bq_f   = conv + 844800;
  const float* Wk_f   = conv + 844928;
  const float* bk_f   = conv + 861312;
  const float* Wv_f   = conv + 861440;
  const float* bv_f   = conv + 877824;
  const float* Wo1_f  = conv + 877952;
  const float* bo1_f  = conv + 910720;
  const float* Wo2_f  = conv + 910976;
  const float* bo2_f  = conv + 943744;
  const float* locW1_f= conv + 943872;
  const float* locb1_f= conv + 960256;
  const float* locg_f = conv + 960384;
  const float* locbe_f= conv + 960512;
  const float* locW2_f= conv + 960640;
  const float* locb2_f= conv + 960896;
  const float* sclW1_f= conv + 960960;
  const float* sclb1_f= conv + 977344;
  const float* sclg_f = conv + 977472;
  const float* sclbe_f= conv + 977600;
  const float* sclW2_f= conv + 977728;
  const float* sclb2_f= conv + 977984;

  const size_t SLOT = (size_t)cT*cKN*cH;
  float* geb = big;
  float* o1b = big + SLOT;
  float* Qb  = big + 2*SLOT;
  float* Kb  = big + 3*SLOT;
  float* Vb  = big + 4*SLOT;
  float* locsc = big + 5*SLOT;
  unsigned char* maskb = (unsigned char*)(locsc + (size_t)cT*cKN*2);
  float* t1 = Qb;        // spans slots 2-3 (Q/K dead after attn)
  float* social = Vb;    // overlays V after attention

  Ptrs ptrs;
  for (int i = 0; i < 37; ++i) ptrs.p[i] = d_in[i];

  k_detect<<<1, 64, 0, stream>>>((const unsigned short*)d_in[0], flagp, (unsigned int*)d_out);
  k_convert<<<(CONV_TOTAL+255)/256, 256, 0, stream>>>(ptrs, flagp, conv);
  k_mhp<<<cT*cN/2, 256, 0, stream>>>(ge_f, mhpW_f, mhpb_f, mhpg_f, mhpbe_f, geb);
  k_lstm_seq<<<cKN/4, 256, 0, stream>>>(geb, o1b, hs_f, cn_f, (const float*)0,
                                        l1Wih_f, l1Whh_f, l1b_f, 1);
  k_heads<<<cT*cKN/4, 256, 0, stream>>>(o1b, locW1_f,locb1_f,locg_f,locbe_f,locW2_f,locb2_f,
                                        sclW1_f,sclb1_f,sclg_f,sclbe_f,sclW2_f,sclb2_f,
                                        d_out, 0, locsc, mx_f, sv_f, flagp);
  k_mask<<<cS*cT, 256, 0, stream>>>(locsc, maskb);
  k_qkv<<<cT*cKN/16, 256, 0, stream>>>(o1b, Wq_f,bq_f, Wk_f,bk_f, Wv_f,bv_f, Qb, Kb, Vb);
  {
    dim3 ag(5, 4, cS*cT);
    k_attn<<<ag, 256, 0, stream>>>(Qb, Kb, Vb, maskb, o1b);   // ctx overlays out1
  }
  k_wo1<<<cT*cKN/8, 256, 0, stream>>>(o1b, Wo1_f, bo1_f, t1);
  k_wo2<<<cT*cKN/16, 256, 0, stream>>>(t1, Wo2_f, bo2_f, social);
  k_lstm_seq<<<cKN/4, 256, 0, stream>>>(geb, o1b, hs_f, cn_f, social,
                                        l2Wih_f, l2Whh_f, l2b_f, 2);
  k_heads<<<cT*cKN/4, 256, 0, stream>>>(o1b, locW1_f,locb1_f,locg_f,locbe_f,locW2_f,locb2_f,
                                        sclW1_f,sclb1_f,sclg_f,sclbe_f,sclW2_f,sclb2_f,
                                        d_out, 2, (float*)0, mx_f, sv_f, flagp);
}

// Round 6
// 765.482 us; speedup vs baseline: 1.5132x; 1.5132x over previous
//
#include <hip/hip_runtime.h>
#include <hip/hip_bf16.h>

typedef __hip_bfloat16 bf16_t;

static const int cT  = 12;    // future steps
static const int cN  = 128;   // agents
static const int cH  = 128;   // hidden
static const int cK  = 20;    // modes
static const int cKN = 2560;  // cK*cN
static const int cS  = 4;     // batch split
static const int cNS = 32;    // agents per scene
static const int cL  = 640;   // cK*cNS attention length
static const int cHD = 32;    // head dim

#define CONV_TOTAL 977986

__constant__ int c_off[38] = {0,196608,212992,229376,229632,229888,557568,560128,562688,
  565248,630784,696320,696832,762368,827904,828416,844800,844928,861312,861440,877824,
  877952,910720,910976,943744,943872,960256,960384,960512,960640,960896,960960,977344,
  977472,977600,977728,977984,977986};
__constant__ int c_len[37] = {196608,16384,16384,256,256,327680,2560,2560,2560,
  65536,65536,512,65536,65536,512,16384,128,16384,128,16384,128,
  32768,256,32768,128,16384,128,128,128,256,2,16384,128,128,128,256,2};

struct Ptrs { const void* p[37]; };

typedef __attribute__((ext_vector_type(4))) float f32x4;
typedef __attribute__((ext_vector_type(8))) __bf16 bf16x8;

__device__ __forceinline__ float sigm(float x){ return 1.f/(1.f+expf(-x)); }
__device__ __forceinline__ unsigned short f2h(float x){ return (unsigned short)(__float_as_uint(x)>>16); }
__device__ __forceinline__ float hif(float x){ return __uint_as_float(__float_as_uint(x)&0xFFFF0000u); }

// dtype sniffing + NaN canary
__global__ __launch_bounds__(256) void k_detect(const unsigned short* ge_u16, int* flagp, unsigned int* outw){
  __shared__ int cnt;
  if (threadIdx.x == 0) cnt = 0;
  __syncthreads();
  int ok = 0;
  for (int i = threadIdx.x; i < 128; i += 64){
    unsigned short u = ge_u16[2*i];
    int ex = (u >> 7) & 0xFF;
    if (ex >= 100 && ex <= 140) ok++;
  }
  atomicAdd(&cnt, ok);
  __syncthreads();
  if (threadIdx.x == 0){
    *flagp = (cnt >= 96) ? 1 : 0;
    outw[0] = 0x7FC07FC0u;
  }
}

// convert all 37 inputs to fp32 into the conv region
__global__ __launch_bounds__(256) void k_convert(Ptrs ptrs, const int* flagp, float* dst){
  int g = blockIdx.x*256 + threadIdx.x;
  if (g >= CONV_TOTAL) return;
  int flag = *flagp;
  int seg = 0;
  while (seg < 36 && g >= c_off[seg+1]) ++seg;
  int local = g - c_off[seg];
  if (local >= c_len[seg]) return;
  float v;
  if (flag) v = __bfloat162float(((const bf16_t*)ptrs.p[seg])[local]);
  else      v = ((const float*)ptrs.p[seg])[local];
  dst[g] = v;
}

// ge = relu(LN_2560(x @ mhp_W + b)), 2 rows per block, weight reuse across rows
__global__ __launch_bounds__(256) void k_mhp(const float* x, const float* W, const float* b,
                      const float* g, const float* be, float* out){
  const int ROWS = 2;
  int r0 = blockIdx.x*ROWS;
  __shared__ float xs[ROWS][cH];
  __shared__ float red[256][3];
  int tid = threadIdx.x;
  if (tid < ROWS*32){
    int rr = tid>>5, u4 = tid&31;
    ((float4*)&xs[rr][0])[u4] = ((const float4*)x)[(r0+rr)*32 + u4];
  }
  __syncthreads();
  float y[ROWS][10];
  #pragma unroll
  for (int m = 0; m < 10; ++m){ float bb = b[tid + 256*m]; y[0][m] = bb; y[1][m] = bb; }
  for (int i = 0; i < cH; ++i){
    float x0 = xs[0][i], x1 = xs[1][i];
    const float* wr = W + i*2560 + tid;
    #pragma unroll
    for (int m = 0; m < 10; ++m){
      float w = wr[256*m];
      y[0][m] += x0*w; y[1][m] += x1*w;
    }
  }
  float ps0 = 0.f, ps1 = 0.f;
  #pragma unroll
  for (int m = 0; m < 10; ++m){ ps0 += y[0][m]; ps1 += y[1][m]; }
  red[tid][0] = ps0; red[tid][1] = ps1; __syncthreads();
  for (int s2 = 128; s2 > 0; s2 >>= 1){
    if (tid < s2){ red[tid][0] += red[tid+s2][0]; red[tid][1] += red[tid+s2][1]; }
    __syncthreads();
  }
  float mean0 = red[0][0]*(1.f/2560.f), mean1 = red[0][1]*(1.f/2560.f);
  __syncthreads();
  float pv0 = 0.f, pv1 = 0.f;
  #pragma unroll
  for (int m = 0; m < 10; ++m){
    float d0 = y[0][m]-mean0, d1 = y[1][m]-mean1;
    pv0 += d0*d0; pv1 += d1*d1;
  }
  red[tid][0] = pv0; red[tid][1] = pv1; __syncthreads();
  for (int s2 = 128; s2 > 0; s2 >>= 1){
    if (tid < s2){ red[tid][0] += red[tid+s2][0]; red[tid][1] += red[tid+s2][1]; }
    __syncthreads();
  }
  float inv0 = rsqrtf(red[0][0]*(1.f/2560.f) + 1e-5f);
  float inv1 = rsqrtf(red[0][1]*(1.f/2560.f) + 1e-5f);
  #pragma unroll
  for (int rr = 0; rr < ROWS; ++rr){
    int rg = r0 + rr;
    int t = rg >> 7, nn = rg & 127;
    float mean = rr ? mean1 : mean0;
    float inv  = rr ? inv1  : inv0;
    #pragma unroll
    for (int m = 0; m < 10; ++m){
      int col = tid + 256*m;
      float z = (y[rr][m]-mean)*inv*g[col] + be[col];
      z = fmaxf(z, 0.f);
      int k = col >> 7, hh2 = col & 127;
      out[((t*cKN) + k*cN + nn)*cH + hh2] = z;
    }
  }
}

// round-12: preconvert the 4 LSTM weight matrices [128][512] into
// fragment-ordered split-bf16 arrays (per mat: 65536 hi + 65536 lo ushorts,
// layout ((n*4+s)*64+l)*8+e with k = 32s + 16(e>>2) + 4g + (e&3), col=16n+(l&15)).
// Output overlays the dead mhp_W region (1.31 MB >= 1 MB). One-time, ~10us.
__global__ __launch_bounds__(256) void k_wprep(const float* w0, const float* w1,
    const float* w2, const float* w3, unsigned short* out){
  int idx = blockIdx.x*256 + threadIdx.x;   // 32768 total
  int m = idx >> 13;
  int rest = idx & 8191;
  int n = rest >> 8;
  int s = (rest >> 6) & 3;
  int l = rest & 63;
  int g = l >> 4, c16 = l & 15;
  const float* W = (m==0) ? w0 : ((m==1) ? w1 : ((m==2) ? w2 : w3));
  unsigned short hi[8], lo[8];
  #pragma unroll
  for (int e = 0; e < 8; ++e){
    int k = 32*s + 16*(e>>2) + 4*g + (e&3);
    float v = W[k*512 + 16*n + c16];
    hi[e] = f2h(v); lo[e] = f2h(v - hif(v));
  }
  size_t base = (size_t)m*131072 + (size_t)((n*4 + s)*64 + l)*8;
  *(uint4*)&out[base]         = *(const uint4*)hi;
  *(uint4*)&out[base + 65536] = *(const uint4*)lo;
}

// round-12: MFMA LSTM. The scalar kernel was pinned at ~348us by the per-block
// weight stream (512KB/step) - more rows starves occupancy, fewer rows doubles
// the stream. MFMA amortizes it: block = 16 rows (one M-tile), 8 waves, wave w
// owns state cols 16w..16w+15 via gate tiles {w,w+8,w+16,w+24} (i,f,g,o columns
// land lane-locally in the D-frag: col=lane&15, row=4(lane>>4)+r - the
// HW-validated mapping from the attention kernel). c/h live in registers in
// D-layout; h redistributes per step through an 8KB fragment-ordered LDS buffer
// (bijective producer slots, consumers read aligned b128). x frags read straight
// from ge. Split-bf16 3-term products (validated accuracy scheme). 96 MFMA +
// 2 barriers per step; weights stream as coalesced 16B fragment loads from L2.
__global__ __launch_bounds__(512) void k_lstm_mfma(const float* ge, float* outh,
    const float* hs0, const float* cn0, const float* soc,
    const unsigned short* wfA, const unsigned short* wfB,
    const float* bias, int phase){
  int r0 = blockIdx.x * 16;
  int tid = threadIdx.x;
  int w = tid >> 6, l = tid & 63;
  int g = l >> 4, c16 = l & 15;
  int scol = w*16 + c16;                 // state col owned by this lane
  __shared__ unsigned short HFh[4][64][8], HFl[4][64][8];   // 8 KB
  // producer slot constants: scol -> (s, gf, e); lane writes rows 4g+r
  int ps = scol >> 5, prem = scol & 31;
  int pgf = (prem >> 2) & 3;
  int pe  = ((prem >> 4) << 2) + (prem & 3);
  float c[4], h[4];
  #pragma unroll
  for (int r = 0; r < 4; ++r){
    int nn = (r0 + 4*g + r) & 127;
    c[r] = cn0[nn*cH + scol];
    h[r] = hs0[nn*cH + scol];
  }
  float bias_t[4];
  #pragma unroll
  for (int tt = 0; tt < 4; ++tt) bias_t[tt] = bias[tt*128 + scol];
  for (int t = 0; t < cT; ++t){
    if (phase == 2){
      #pragma unroll
      for (int r = 0; r < 4; ++r){
        float sv = soc[(size_t)t*cKN*cH + (size_t)(r0 + 4*g + r)*cH + scol];
        c[r] += sv;
        h[r] += tanhf(c[r]);
      }
    }
    #pragma unroll
    for (int r = 0; r < 4; ++r){
      HFh[ps][pgf*16 + 4*g + r][pe] = f2h(h[r]);
      HFl[ps][pgf*16 + 4*g + r][pe] = f2h(h[r] - hif(h[r]));
    }
    __syncthreads();                      // h fragment buffer complete
    bf16x8 hh[4], hl[4], xh[4], xl[4];
    #pragma unroll
    for (int s = 0; s < 4; ++s){
      hh[s] = *(const bf16x8*)&HFh[s][l][0];
      hl[s] = *(const bf16x8*)&HFl[s][l][0];
    }
    {
      const f32x4* gp = (const f32x4*)ge + ((size_t)t*cKN + r0 + c16)*32;
      #pragma unroll
      for (int s = 0; s < 4; ++s){
        f32x4 qa = gp[8*s + g], qb = gp[8*s + 4 + g];
        union { unsigned short u[8]; bf16x8 v; } uh, ul;
        #pragma unroll
        for (int m2 = 0; m2 < 4; ++m2){
          float a0 = qa[m2], b0 = qb[m2];
          uh.u[m2]   = f2h(a0); ul.u[m2]   = f2h(a0 - hif(a0));
          uh.u[4+m2] = f2h(b0); ul.u[4+m2] = f2h(b0 - hif(b0));
        }
        xh[s] = uh.v; xl[s] = ul.v;
      }
    }
    __syncthreads();                      // all HF reads done before next write
    f32x4 a4[4];
    #pragma unroll
    for (int tt = 0; tt < 4; ++tt){
      int n = w + 8*tt;
      f32x4 acc = {bias_t[tt], bias_t[tt], bias_t[tt], bias_t[tt]};
      #pragma unroll
      for (int s = 0; s < 4; ++s){
        size_t fo = (size_t)((n*4 + s)*64 + l)*8;
        bf16x8 Ah = *(const bf16x8*)&wfA[fo];
        bf16x8 Al = *(const bf16x8*)&wfA[65536 + fo];
        bf16x8 Bh = *(const bf16x8*)&wfB[fo];
        bf16x8 Bl = *(const bf16x8*)&wfB[65536 + fo];
        acc = __builtin_amdgcn_mfma_f32_16x16x32_bf16(xl[s], Ah, acc, 0, 0, 0);
        acc = __builtin_amdgcn_mfma_f32_16x16x32_bf16(xh[s], Al, acc, 0, 0, 0);
        acc = __builtin_amdgcn_mfma_f32_16x16x32_bf16(xh[s], Ah, acc, 0, 0, 0);
        acc = __builtin_amdgcn_mfma_f32_16x16x32_bf16(hl[s], Bh, acc, 0, 0, 0);
        acc = __builtin_amdgcn_mfma_f32_16x16x32_bf16(hh[s], Bl, acc, 0, 0, 0);
        acc = __builtin_amdgcn_mfma_f32_16x16x32_bf16(hh[s], Bh, acc, 0, 0, 0);
      }
      a4[tt] = acc;
    }
    #pragma unroll
    for (int r = 0; r < 4; ++r){
      float ig = sigm(a4[0][r]), fg = sigm(a4[1][r]);
      float gg = tanhf(a4[2][r]), og = sigm(a4[3][r]);
      c[r] = fg*c[r] + ig*gg;
      h[r] = og*tanhf(c[r]);
      outh[(size_t)t*cKN*cH + (size_t)(r0 + 4*g + r)*cH + scol] = h[r];
    }
  }
}

// loc & scale heads, wave-local: wave = (head, row-pair), shfl reductions, no trees.
__global__ __launch_bounds__(256) void k_heads(const float* x,
  const float* lW1, const float* lb1, const float* lg, const float* lbe, const float* lW2, const float* lb2v,
  const float* sW1, const float* sb1, const float* sg, const float* sbe, const float* sW2, const float* sb2v,
  void* outv, int q0, float* locsc, const float* maxv, const float* svp, const int* flagp){
  const int ROWS = 4;
  int r0 = blockIdx.x*ROWS;
  __shared__ float xs[ROWS][cH];
  int tid = threadIdx.x;
  if (tid < ROWS*32){
    int rr = tid>>5, u4 = tid&31;
    ((float4*)&xs[rr][0])[u4] = ((const float4*)x)[(size_t)(r0+rr)*32 + u4];
  }
  __syncthreads();
  int wv = tid >> 6, lane = tid & 63;
  int head = wv & 1;
  int ra = (wv >> 1)*2, rb = ra + 1;     // local rows
  const float* W1 = head ? sW1 : lW1;
  const float* b1 = head ? sb1 : lb1;
  const float* gv = head ? sg  : lg;
  const float* be = head ? sbe : lbe;
  const float* W2 = head ? sW2 : lW2;
  const float* b2 = head ? sb2v: lb2v;
  int j0 = lane, j1 = lane + 64;
  float a00 = b1[j0], a01 = b1[j1];
  float a10 = a00, a11 = a01;
  for (int i = 0; i < cH; ++i){
    float w0 = W1[i*cH + j0], w1 = W1[i*cH + j1];
    float xa = xs[ra][i], xb = xs[rb][i];
    a00 += xa*w0; a01 += xa*w1;
    a10 += xb*w0; a11 += xb*w1;
  }
  float s0 = a00 + a01, s1 = a10 + a11;
  #pragma unroll
  for (int off = 1; off < 64; off <<= 1){
    s0 += __shfl_xor(s0, off);
    s1 += __shfl_xor(s1, off);
  }
  float mean0 = s0*(1.f/128.f), mean1 = s1*(1.f/128.f);
  float d00 = a00-mean0, d01 = a01-mean0, d10 = a10-mean1, d11 = a11-mean1;
  float v0 = d00*d00 + d01*d01, v1 = d10*d10 + d11*d11;
  #pragma unroll
  for (int off = 1; off < 64; off <<= 1){
    v0 += __shfl_xor(v0, off);
    v1 += __shfl_xor(v1, off);
  }
  float inv0 = rsqrtf(v0*(1.f/128.f) + 1e-5f);
  float inv1 = rsqrtf(v1*(1.f/128.f) + 1e-5f);
  float g0 = gv[j0], g1 = gv[j1], be0 = be[j0], be1 = be[j1];
  float z00 = fmaxf(d00*inv0*g0 + be0, 0.f);
  float z01 = fmaxf(d01*inv0*g1 + be1, 0.f);
  float z10 = fmaxf(d10*inv1*g0 + be0, 0.f);
  float z11 = fmaxf(d11*inv1*g1 + be1, 0.f);
  float w2a0 = W2[j0*2+0], w2a1 = W2[j0*2+1];
  float w2b0 = W2[j1*2+0], w2b1 = W2[j1*2+1];
  float oa0 = z00*w2a0 + z01*w2b0;   // row ra, out 0
  float oa1 = z00*w2a1 + z01*w2b1;   // row ra, out 1
  float ob0 = z10*w2a0 + z11*w2b0;
  float ob1 = z10*w2a1 + z11*w2b1;
  #pragma unroll
  for (int off = 1; off < 64; off <<= 1){
    oa0 += __shfl_xor(oa0, off);
    oa1 += __shfl_xor(oa1, off);
    ob0 += __shfl_xor(ob0, off);
    ob1 += __shfl_xor(ob1, off);
  }
  if (lane == 0){
    int flag = *flagp;
    float bias0 = b2[0], bias1 = b2[1];
    float ro[2][2] = {{oa0 + bias0, oa1 + bias1},{ob0 + bias0, ob1 + bias1}};
    int lr[2] = {ra, rb};
    for (int e = 0; e < 2; ++e){
      int rg = r0 + lr[e];
      int t = rg / cKN, rem = rg - t*cKN;
      int k = rem >> 7, nn = rem & 127;
      float u0 = ro[e][0], u1 = ro[e][1];
      if (head == 0){
        size_t oi = (((size_t)q0*cK + k)*cN + nn)*(cT*2) + t*2;
        if (flag){ ((bf16_t*)outv)[oi] = __float2bfloat16(u0); ((bf16_t*)outv)[oi+1] = __float2bfloat16(u1); }
        else     { ((float*)outv)[oi] = u0; ((float*)outv)[oi+1] = u1; }
        if (locsc){
          locsc[((size_t)t*cKN + rem)*2 + 0] = u0*maxv[nn*2+0] + svp[nn*2+0];
          locsc[((size_t)t*cKN + rem)*2 + 1] = u1*maxv[nn*2+1] + svp[nn*2+1];
        }
      } else {
        float e0 = (u0 > 0.f ? u0 : expm1f(u0)) + 1.001f;
        float e1 = (u1 > 0.f ? u1 : expm1f(u1)) + 1.001f;
        size_t oi = (((size_t)(q0+1)*cK + k)*cN + nn)*(cT*2) + t*2;
        if (flag){ ((bf16_t*)outv)[oi] = __float2bfloat16(e0); ((bf16_t*)outv)[oi+1] = __float2bfloat16(e1); }
        else     { ((float*)outv)[oi] = e0; ((float*)outv)[oi+1] = e1; }
      }
    }
  }
}

__global__ __launch_bounds__(256) void k_mask(const float* locsc, unsigned char* m){
  int st = blockIdx.x;
  int s = st / cT, t = st - s*cT;
  __shared__ float lx[cK][cNS], ly[cK][cNS];
  int tid = threadIdx.x;
  for (int p = tid; p < cK*cNS; p += 256){
    int k = p >> 5, i = p & 31;
    int row = t*cKN + k*cN + s*cNS + i;
    lx[k][i] = locsc[row*2+0];
    ly[k][i] = locsc[row*2+1];
  }
  __syncthreads();
  for (int p = tid; p < 1024; p += 256){
    int i = p >> 5, j = p & 31;
    bool any = false;
    for (int k = 0; k < cK; ++k){
      float dx = fabsf(lx[k][i]-lx[k][j]);
      float dy = fabsf(ly[k][i]-ly[k][j]);
      any = any || ((dx < 10.f) && (dy < 10.f));
    }
    m[st*1024 + p] = any ? 1 : 0;
  }
}

// QKV projection, 16 rows/block, weight reuse for 8 rows/thread
__global__ __launch_bounds__(256) void k_qkv(const float* x,
  const float* Wq, const float* bq, const float* Wk, const float* bk,
  const float* Wv, const float* bv,
  float* Q, float* K2, float* V){
  const int ROWS = 16;
  int r0 = blockIdx.x*ROWS;
  __shared__ float xs[ROWS][cH];
  int tid = threadIdx.x;
  for (int p = tid; p < ROWS*32; p += 256){
    int rr = p>>5, u4 = p&31;
    ((float4*)&xs[rr][0])[u4] = ((const float4*)x)[(size_t)(r0+rr)*32 + u4];
  }
  __syncthreads();
  int cl = tid & 127, half = tid >> 7;
  float aq[8], ak[8], av[8];
  float bq0 = bq[cl], bk0 = bk[cl], bv0 = bv[cl];
  #pragma unroll
  for (int r = 0; r < 8; ++r){ aq[r] = bq0; ak[r] = bk0; av[r] = bv0; }
  for (int i = 0; i < cH; ++i){
    float wq = Wq[i*cH+cl], wk = Wk[i*cH+cl], wv = Wv[i*cH+cl];
    #pragma unroll
    for (int q2 = 0; q2 < 8; ++q2){
      float xi = xs[half + 2*q2][i];
      aq[q2] += xi*wq; ak[q2] += xi*wk; av[q2] += xi*wv;
    }
  }
  #pragma unroll
  for (int q2 = 0; q2 < 8; ++q2){
    size_t gi = (size_t)(r0 + half + 2*q2)*cH + cl;
    Q[gi] = aq[q2]; K2[gi] = ak[q2]; V[gi] = av[q2];
  }
}

// round-10: MFMA attention (validated). Split-bf16 3-mfma products; QK^T =
// mfma(A=K, B=Q) with k-map k=16(e>>2)+4g+(e&3); PV A-frag = lane's own
// S-accumulator. No-max softmax. K/V staged to LDS in fragment order.
__global__ __launch_bounds__(256) void k_attn(const float* Q, const float* Kx, const float* V,
                       const unsigned char* msk, float* ctx){
  int qs   = blockIdx.x;        // 0..4 : group of 8 q-tiles (2 per wave)
  int head = blockIdx.y;        // 0..3
  int st   = blockIdx.z;        // s*cT + t
  int s = st / cT, t = st - s*cT;
  __shared__ unsigned short KLh[2][1024], KLl[2][1024], VLh[2][1024], VLl[2][1024]; // 16 KB
  int tid = threadIdx.x;
  int w = tid >> 6, lane = tid & 63;
  int g = lane >> 4, col = lane & 15;
  const float scl = 0.17677669529663687f;   // 1/sqrt(32)

  // mask rows (q_agent = col, col+16) packed to 32-bit words (byte->bit)
  unsigned int mw0 = 0, mw1 = 0;
  {
    const unsigned int* mr0 = (const unsigned int*)(msk + st*1024 + col*32);
    const unsigned int* mr1 = (const unsigned int*)(msk + st*1024 + (16+col)*32);
    #pragma unroll
    for (int j2 = 0; j2 < 8; ++j2){
      mw0 |= (((mr0[j2] * 0x01020408u) >> 24) & 0xFu) << (4*j2);
      mw1 |= (((mr1[j2] * 0x01020408u) >> 24) & 0xFu) << (4*j2);
    }
  }

  // Q fragments (pre-scaled by scl), 2 tiles per wave; B col = lane&15
  bf16x8 Qh[2], Ql[2];
  int modes[2], ahs[2];
  #pragma unroll
  for (int i = 0; i < 2; ++i){
    int tt = qs*8 + 4*i + w;       // 0..39
    int mode = tt >> 1, ah = tt & 1;
    modes[i] = mode; ahs[i] = ah;
    int qrow = t*cKN + mode*cN + s*cNS + ah*16 + col;
    const f32x4* qp = (const f32x4*)Q + (size_t)qrow*32 + head*8;
    f32x4 qa = qp[g], qb = qp[4+g];     // dims 4g..4g+3, 16+4g..16+4g+3
    union { unsigned short u[8]; bf16x8 v; } uh, ul;
    #pragma unroll
    for (int m = 0; m < 4; ++m){
      float x0 = qa[m]*scl;
      uh.u[m] = f2h(x0);
      ul.u[m] = f2h(x0 - hif(x0));
      float x1 = qb[m]*scl;
      uh.u[4+m] = f2h(x1);
      ul.u[4+m] = f2h(x1 - hif(x1));
    }
    Qh[i] = uh.v; Ql[i] = ul.v;
  }

  // staging indices
  int kk = tid >> 3, f4 = tid & 7;                 // K: key kk, dims 4*f4..+3
  int kwi = (((kk>>4)*4 + (f4&3))*16 + (kk&15))*8 + (f4>>2)*4;
  int vd = tid & 31, quad = tid >> 5;              // V: dim vd, keys base..+3
  int vkey = (quad>>2)*16 + (quad&3)*4;
  int vwi = (((vd>>4)*4 + (quad&3))*16 + (vd&15))*8 + (quad>>2)*4;

  const size_t cstepK = (size_t)cN*32;             // float4 per chunk (one mode)
  const size_t cstepV = (size_t)cN*128;            // float per chunk
  const float4* kptr = (const float4*)Kx + ((size_t)(t*cKN + s*cNS + kk))*32 + head*8 + f4;
  const float*  vptr = V + ((size_t)(t*cKN + s*cNS + vkey))*128 + head*32 + vd;

  float4 kv; float vm0, vm1, vm2, vm3;
  kv = *kptr; kptr += cstepK;
  vm0 = vptr[0]; vm1 = vptr[128]; vm2 = vptr[256]; vm3 = vptr[384]; vptr += cstepV;
  {
    unsigned int h0 = (unsigned int)f2h(kv.x) | ((unsigned int)f2h(kv.y)<<16);
    unsigned int h1 = (unsigned int)f2h(kv.z) | ((unsigned int)f2h(kv.w)<<16);
    float r0 = kv.x-hif(kv.x), r1 = kv.y-hif(kv.y), r2 = kv.z-hif(kv.z), r3 = kv.w-hif(kv.w);
    unsigned int l0 = (unsigned int)f2h(r0) | ((unsigned int)f2h(r1)<<16);
    unsigned int l1 = (unsigned int)f2h(r2) | ((unsigned int)f2h(r3)<<16);
    *(uint2*)&KLh[0][kwi] = make_uint2(h0,h1);
    *(uint2*)&KLl[0][kwi] = make_uint2(l0,l1);
    unsigned int vh0 = (unsigned int)f2h(vm0) | ((unsigned int)f2h(vm1)<<16);
    unsigned int vh1 = (unsigned int)f2h(vm2) | ((unsigned int)f2h(vm3)<<16);
    float s0 = vm0-hif(vm0), s1 = vm1-hif(vm1), s2 = vm2-hif(vm2), s3 = vm3-hif(vm3);
    unsigned int vl0 = (unsigned int)f2h(s0) | ((unsigned int)f2h(s1)<<16);
    unsigned int vl1 = (unsigned int)f2h(s2) | ((unsigned int)f2h(s3)<<16);
    *(uint2*)&VLh[0][vwi] = make_uint2(vh0,vh1);
    *(uint2*)&VLl[0][vwi] = make_uint2(vl0,vl1);
  }
  __syncthreads();

  const f32x4 Z = {0.f, 0.f, 0.f, 0.f};
  f32x4 O[2][2] = {{Z, Z}, {Z, Z}};
  float lac[2] = {0.f, 0.f};

  for (int ch = 0; ch < 20; ++ch){
    int par = ch & 1;
    if (ch < 19){
      kv = *kptr; kptr += cstepK;
      vm0 = vptr[0]; vm1 = vptr[128]; vm2 = vptr[256]; vm3 = vptr[384]; vptr += cstepV;
    }
    // fragment reads (shared across this wave's tiles)
    bf16x8 KAh0 = *(const bf16x8*)&KLh[par][( g      *16 + col)*8];
    bf16x8 KAl0 = *(const bf16x8*)&KLl[par][( g      *16 + col)*8];
    bf16x8 KAh1 = *(const bf16x8*)&KLh[par][((4 + g) *16 + col)*8];
    bf16x8 KAl1 = *(const bf16x8*)&KLl[par][((4 + g) *16 + col)*8];
    bf16x8 VBh0 = *(const bf16x8*)&VLh[par][( g      *16 + col)*8];
    bf16x8 VBl0 = *(const bf16x8*)&VLl[par][( g      *16 + col)*8];
    bf16x8 VBh1 = *(const bf16x8*)&VLh[par][((4 + g) *16 + col)*8];
    bf16x8 VBl1 = *(const bf16x8*)&VLl[par][((4 + g) *16 + col)*8];
    #pragma unroll
    for (int i = 0; i < 2; ++i){
      f32x4 sa = Z, sb = Z;
      sa = __builtin_amdgcn_mfma_f32_16x16x32_bf16(KAl0, Qh[i], sa, 0, 0, 0);
      sa = __builtin_amdgcn_mfma_f32_16x16x32_bf16(KAh0, Ql[i], sa, 0, 0, 0);
      sa = __builtin_amdgcn_mfma_f32_16x16x32_bf16(KAh0, Qh[i], sa, 0, 0, 0);
      sb = __builtin_amdgcn_mfma_f32_16x16x32_bf16(KAl1, Qh[i], sb, 0, 0, 0);
      sb = __builtin_amdgcn_mfma_f32_16x16x32_bf16(KAh1, Ql[i], sb, 0, 0, 0);
      sb = __builtin_amdgcn_mfma_f32_16x16x32_bf16(KAh1, Qh[i], sb, 0, 0, 0);
      unsigned int mw = ahs[i] ? mw1 : mw0;
      float p[8];
      #pragma unroll
      for (int r = 0; r < 4; ++r){
        float e0 = __expf(sa[r]);
        float e1 = __expf(sb[r]);
        p[r]   = ((mw >> (4*g + r)) & 1)        ? e0 : 0.f;
        p[4+r] = ((mw >> (16 + 4*g + r)) & 1)   ? e1 : 0.f;
      }
      lac[i] += ((p[0]+p[1])+(p[2]+p[3])) + ((p[4]+p[5])+(p[6]+p[7]));
      union { unsigned short u[8]; bf16x8 v; } Ph, Pl;
      #pragma unroll
      for (int e = 0; e < 8; ++e){
        Ph.u[e] = f2h(p[e]);
        Pl.u[e] = f2h(p[e] - hif(p[e]));
      }
      O[i][0] = __builtin_amdgcn_mfma_f32_16x16x32_bf16(Pl.v, VBh0, O[i][0], 0, 0, 0);
      O[i][0] = __builtin_amdgcn_mfma_f32_16x16x32_bf16(Ph.v, VBl0, O[i][0], 0, 0, 0);
      O[i][0] = __builtin_amdgcn_mfma_f32_16x16x32_bf16(Ph.v, VBh0, O[i][0], 0, 0, 0);
      O[i][1] = __builtin_amdgcn_mfma_f32_16x16x32_bf16(Pl.v, VBh1, O[i][1], 0, 0, 0);
      O[i][1] = __builtin_amdgcn_mfma_f32_16x16x32_bf16(Ph.v, VBl1, O[i][1], 0, 0, 0);
      O[i][1] = __builtin_amdgcn_mfma_f32_16x16x32_bf16(Ph.v, VBh1, O[i][1], 0, 0, 0);
    }
    __syncthreads();   // all frag reads of [par] done
    if (ch < 19){
      int nb = 1 - par;
      unsigned int h0 = (unsigned int)f2h(kv.x) | ((unsigned int)f2h(kv.y)<<16);
      unsigned int h1 = (unsigned int)f2h(kv.z) | ((unsigned int)f2h(kv.w)<<16);
      float r0 = kv.x-hif(kv.x), r1 = kv.y-hif(kv.y), r2 = kv.z-hif(kv.z), r3 = kv.w-hif(kv.w);
      unsigned int l0 = (unsigned int)f2h(r0) | ((unsigned int)f2h(r1)<<16);
      unsigned int l1 = (unsigned int)f2h(r2) | ((unsigned int)f2h(r3)<<16);
      *(uint2*)&KLh[nb][kwi] = make_uint2(h0,h1);
      *(uint2*)&KLl[nb][kwi] = make_uint2(l0,l1);
      unsigned int vh0 = (unsigned int)f2h(vm0) | ((unsigned int)f2h(vm1)<<16);
      unsigned int vh1 = (unsigned int)f2h(vm2) | ((unsigned int)f2h(vm3)<<16);
      float s0 = vm0-hif(vm0), s1 = vm1-hif(vm1), s2 = vm2-hif(vm2), s3 = vm3-hif(vm3);
      unsigned int vl0 = (unsigned int)f2h(s0) | ((unsigned int)f2h(s1)<<16);
      unsigned int vl1 = (unsigned int)f2h(s2) | ((unsigned int)f2h(s3)<<16);
      *(uint2*)&VLh[nb][vwi] = make_uint2(vh0,vh1);
      *(uint2*)&VLl[nb][vwi] = make_uint2(vl0,vl1);
    }
    __syncthreads();   // next buffer visible
  }

  // epilogue: row denominators + normalized writes
  #pragma unroll
  for (int i = 0; i < 2; ++i){
    float lsum = lac[i];
    lsum += __shfl_xor(lsum, 16);
    lsum += __shfl_xor(lsum, 32);
    int base = t*cKN + modes[i]*cN + s*cNS + ahs[i]*16;
    #pragma unroll
    for (int r = 0; r < 4; ++r){
      float lq = __shfl(lsum, 4*g + r);
      float rinv = 1.f / lq;
      float* cp = ctx + (size_t)(base + 4*g + r)*cH + head*cHD;
      cp[col]      = O[i][0][r] * rinv;
      cp[col+16]   = O[i][1][r] * rinv;
    }
  }
}

// Wo1 + relu, 8 rows/block, weight reuse
__global__ __launch_bounds__(256) void k_wo1(const float* x, const float* W, const float* b, float* o){
  const int ROWS = 8;
  int r0 = blockIdx.x*ROWS;
  __shared__ float xs[ROWS][cH];
  int tid = threadIdx.x;
  {
    int rr = tid>>5, u4 = tid&31;
    ((float4*)&xs[rr][0])[u4] = ((const float4*)x)[(size_t)(r0+rr)*32 + u4];
  }
  __syncthreads();
  float a[8];
  float bb = b[tid];
  #pragma unroll
  for (int r = 0; r < 8; ++r) a[r] = bb;
  for (int i = 0; i < cH; ++i){
    float w = W[i*256 + tid];
    #pragma unroll
    for (int r = 0; r < 8; ++r) a[r] += xs[r][i]*w;
  }
  #pragma unroll
  for (int r = 0; r < 8; ++r) o[(size_t)(r0+r)*256 + tid] = fmaxf(a[r], 0.f);
}

// Wo2, 16 rows/block, weight reuse
__global__ __launch_bounds__(256) void k_wo2(const float* x, const float* W, const float* b, float* o){
  const int ROWS = 16;
  int r0 = blockIdx.x*ROWS;
  __shared__ float xs[ROWS][256];
  int tid = threadIdx.x;
  for (int p = tid; p < ROWS*64; p += 256){
    int rr = p>>6, u4 = p&63;
    ((float4*)&xs[rr][0])[u4] = ((const float4*)x)[(size_t)(r0+rr)*64 + u4];
  }
  __syncthreads();
  int cl = tid & 127, half = tid >> 7;
  float a[8];
  float bb = b[cl];
  #pragma unroll
  for (int r = 0; r < 8; ++r) a[r] = bb;
  for (int i = 0; i < 256; ++i){
    float w = W[i*cH + cl];
    #pragma unroll
    for (int q2 = 0; q2 < 8; ++q2) a[q2] += xs[half + 2*q2][i]*w;
  }
  #pragma unroll
  for (int q2 = 0; q2 < 8; ++q2) o[(size_t)(r0 + half + 2*q2)*cH + cl] = a[q2];
}

extern "C" void kernel_launch(void* const* d_in, const int* in_sizes, int n_in,
                              void* d_out, int out_size, void* d_ws, size_t ws_size,
                              hipStream_t stream){
  (void)in_sizes; (void)n_in; (void)out_size; (void)ws_size;

  int*   flagp = (int*)d_ws;
  float* conv  = (float*)d_ws + 64;
  float* big   = (float*)d_ws + 978112;

  const float* ge_f   = conv + 0;
  const float* hs_f   = conv + 196608;
  const float* cn_f   = conv + 212992;
  const float* sv_f   = conv + 229376;
  const float* mx_f   = conv + 229632;
  const float* mhpW_f = conv + 229888;
  const float* mhpb_f = conv + 557568;
  const float* mhpg_f = conv + 560128;
  const float* mhpbe_f= conv + 562688;
  const float* l1Wih_f= conv + 565248;
  const float* l1Whh_f= conv + 630784;
  const float* l1b_f  = conv + 696320;
  const float* l2Wih_f= conv + 696832;
  const float* l2Whh_f= conv + 762368;
  const float* l2b_f  = conv + 827904;
  const float* Wq_f   = conv + 828416;
  const float* bq_f   = conv + 844800;
  const float* Wk_f   = conv + 844928;
  const float* bk_f   = conv + 861312;
  const float* Wv_f   = conv + 861440;
  const float* bv_f   = conv + 877824;
  const float* Wo1_f  = conv + 877952;
  const float* bo1_f  = conv + 910720;
  const float* Wo2_f  = conv + 910976;
  const float* bo2_f  = conv + 943744;
  const float* locW1_f= conv + 943872;
  const float* locb1_f= conv + 960256;
  const float* locg_f = conv + 960384;
  const float* locbe_f= conv + 960512;
  const float* locW2_f= conv + 960640;
  const float* locb2_f= conv + 960896;
  const float* sclW1_f= conv + 960960;
  const float* sclb1_f= conv + 977344;
  const float* sclg_f = conv + 977472;
  const float* sclbe_f= conv + 977600;
  const float* sclW2_f= conv + 977728;
  const float* sclb2_f= conv + 977984;

  const size_t SLOT = (size_t)cT*cKN*cH;
  float* geb = big;
  float* o1b = big + SLOT;
  float* Qb  = big + 2*SLOT;
  float* Kb  = big + 3*SLOT;
  float* Vb  = big + 4*SLOT;
  float* locsc = big + 5*SLOT;
  unsigned char* maskb = (unsigned char*)(locsc + (size_t)cT*cKN*2);
  float* t1 = Qb;        // spans slots 2-3 (Q/K dead after attn)
  float* social = Vb;    // overlays V after attention

  // LSTM weight fragments overlay the mhp_W region (1.31 MB, dead after k_mhp)
  unsigned short* wfrag = (unsigned short*)(conv + 229888);

  Ptrs ptrs;
  for (int i = 0; i < 37; ++i) ptrs.p[i] = d_in[i];

  k_detect<<<1, 64, 0, stream>>>((const unsigned short*)d_in[0], flagp, (unsigned int*)d_out);
  k_convert<<<(CONV_TOTAL+255)/256, 256, 0, stream>>>(ptrs, flagp, conv);
  k_mhp<<<cT*cN/2, 256, 0, stream>>>(ge_f, mhpW_f, mhpb_f, mhpg_f, mhpbe_f, geb);
  k_wprep<<<128, 256, 0, stream>>>(l1Wih_f, l1Whh_f, l2Wih_f, l2Whh_f, wfrag);
  k_lstm_mfma<<<160, 512, 0, stream>>>(geb, o1b, hs_f, cn_f, (const float*)0,
                                       wfrag + 0, wfrag + 131072, l1b_f, 1);
  k_heads<<<cT*cKN/4, 256, 0, stream>>>(o1b, locW1_f,locb1_f,locg_f,locbe_f,locW2_f,locb2_f,
                                        sclW1_f,sclb1_f,sclg_f,sclbe_f,sclW2_f,sclb2_f,
                                        d_out, 0, locsc, mx_f, sv_f, flagp);
  k_mask<<<cS*cT, 256, 0, stream>>>(locsc, maskb);
  k_qkv<<<cT*cKN/16, 256, 0, stream>>>(o1b, Wq_f,bq_f, Wk_f,bk_f, Wv_f,bv_f, Qb, Kb, Vb);
  {
    dim3 ag(5, 4, cS*cT);
    k_attn<<<ag, 256, 0, stream>>>(Qb, Kb, Vb, maskb, o1b);   // ctx overlays out1
  }
  k_wo1<<<cT*cKN/8, 256, 0, stream>>>(o1b, Wo1_f, bo1_f, t1);
  k_wo2<<<cT*cKN/16, 256, 0, stream>>>(t1, Wo2_f, bo2_f, social);
  k_lstm_mfma<<<160, 512, 0, stream>>>(geb, o1b, hs_f, cn_f, social,
                                       wfrag + 262144, wfrag + 393216, l2b_f, 2);
  k_heads<<<cT*cKN/4, 256, 0, stream>>>(o1b, locW1_f,locb1_f,locg_f,locbe_f,locW2_f,locb2_f,
                                        sclW1_f,sclb1_f,sclg_f,sclbe_f,sclW2_f,sclb2_f,
                                        d_out, 2, (float*)0, mx_f, sv_f, flagp);
}

// Round 7
// 729.816 us; speedup vs baseline: 1.5871x; 1.0489x over previous
//
#include <hip/hip_runtime.h>
#include <hip/hip_bf16.h>

typedef __hip_bfloat16 bf16_t;

static const int cT  = 12;    // future steps
static const int cN  = 128;   // agents
static const int cH  = 128;   // hidden
static const int cK  = 20;    // modes
static const int cKN = 2560;  // cK*cN
static const int cS  = 4;     // batch split
static const int cNS = 32;    // agents per scene
static const int cL  = 640;   // cK*cNS attention length
static const int cHD = 32;    // head dim

#define CONV_TOTAL 977986

__constant__ int c_off[38] = {0,196608,212992,229376,229632,229888,557568,560128,562688,
  565248,630784,696320,696832,762368,827904,828416,844800,844928,861312,861440,877824,
  877952,910720,910976,943744,943872,960256,960384,960512,960640,960896,960960,977344,
  977472,977600,977728,977984,977986};
__constant__ int c_len[37] = {196608,16384,16384,256,256,327680,2560,2560,2560,
  65536,65536,512,65536,65536,512,16384,128,16384,128,16384,128,
  32768,256,32768,128,16384,128,128,128,256,2,16384,128,128,128,256,2};

struct Ptrs { const void* p[37]; };

typedef __attribute__((ext_vector_type(4))) float f32x4;
typedef __attribute__((ext_vector_type(8))) __bf16 bf16x8;

__device__ __forceinline__ float sigm(float x){ return 1.f/(1.f+expf(-x)); }
__device__ __forceinline__ unsigned short f2h(float x){ return (unsigned short)(__float_as_uint(x)>>16); }
__device__ __forceinline__ float hif(float x){ return __uint_as_float(__float_as_uint(x)&0xFFFF0000u); }

// dtype sniffing + NaN canary
__global__ __launch_bounds__(256) void k_detect(const unsigned short* ge_u16, int* flagp, unsigned int* outw){
  __shared__ int cnt;
  if (threadIdx.x == 0) cnt = 0;
  __syncthreads();
  int ok = 0;
  for (int i = threadIdx.x; i < 128; i += 64){
    unsigned short u = ge_u16[2*i];
    int ex = (u >> 7) & 0xFF;
    if (ex >= 100 && ex <= 140) ok++;
  }
  atomicAdd(&cnt, ok);
  __syncthreads();
  if (threadIdx.x == 0){
    *flagp = (cnt >= 96) ? 1 : 0;
    outw[0] = 0x7FC07FC0u;
  }
}

// convert all 37 inputs to fp32 into the conv region
__global__ __launch_bounds__(256) void k_convert(Ptrs ptrs, const int* flagp, float* dst){
  int g = blockIdx.x*256 + threadIdx.x;
  if (g >= CONV_TOTAL) return;
  int flag = *flagp;
  int seg = 0;
  while (seg < 36 && g >= c_off[seg+1]) ++seg;
  int local = g - c_off[seg];
  if (local >= c_len[seg]) return;
  float v;
  if (flag) v = __bfloat162float(((const bf16_t*)ptrs.p[seg])[local]);
  else      v = ((const float*)ptrs.p[seg])[local];
  dst[g] = v;
}

// ge = relu(LN_2560(x @ mhp_W + b)), 2 rows per block, weight reuse across rows
__global__ __launch_bounds__(256) void k_mhp(const float* x, const float* W, const float* b,
                      const float* g, const float* be, float* out){
  const int ROWS = 2;
  int r0 = blockIdx.x*ROWS;
  __shared__ float xs[ROWS][cH];
  __shared__ float red[256][3];
  int tid = threadIdx.x;
  if (tid < ROWS*32){
    int rr = tid>>5, u4 = tid&31;
    ((float4*)&xs[rr][0])[u4] = ((const float4*)x)[(r0+rr)*32 + u4];
  }
  __syncthreads();
  float y[ROWS][10];
  #pragma unroll
  for (int m = 0; m < 10; ++m){ float bb = b[tid + 256*m]; y[0][m] = bb; y[1][m] = bb; }
  for (int i = 0; i < cH; ++i){
    float x0 = xs[0][i], x1 = xs[1][i];
    const float* wr = W + i*2560 + tid;
    #pragma unroll
    for (int m = 0; m < 10; ++m){
      float w = wr[256*m];
      y[0][m] += x0*w; y[1][m] += x1*w;
    }
  }
  float ps0 = 0.f, ps1 = 0.f;
  #pragma unroll
  for (int m = 0; m < 10; ++m){ ps0 += y[0][m]; ps1 += y[1][m]; }
  red[tid][0] = ps0; red[tid][1] = ps1; __syncthreads();
  for (int s2 = 128; s2 > 0; s2 >>= 1){
    if (tid < s2){ red[tid][0] += red[tid+s2][0]; red[tid][1] += red[tid+s2][1]; }
    __syncthreads();
  }
  float mean0 = red[0][0]*(1.f/2560.f), mean1 = red[0][1]*(1.f/2560.f);
  __syncthreads();
  float pv0 = 0.f, pv1 = 0.f;
  #pragma unroll
  for (int m = 0; m < 10; ++m){
    float d0 = y[0][m]-mean0, d1 = y[1][m]-mean1;
    pv0 += d0*d0; pv1 += d1*d1;
  }
  red[tid][0] = pv0; red[tid][1] = pv1; __syncthreads();
  for (int s2 = 128; s2 > 0; s2 >>= 1){
    if (tid < s2){ red[tid][0] += red[tid+s2][0]; red[tid][1] += red[tid+s2][1]; }
    __syncthreads();
  }
  float inv0 = rsqrtf(red[0][0]*(1.f/2560.f) + 1e-5f);
  float inv1 = rsqrtf(red[0][1]*(1.f/2560.f) + 1e-5f);
  #pragma unroll
  for (int rr = 0; rr < ROWS; ++rr){
    int rg = r0 + rr;
    int t = rg >> 7, nn = rg & 127;
    float mean = rr ? mean1 : mean0;
    float inv  = rr ? inv1  : inv0;
    #pragma unroll
    for (int m = 0; m < 10; ++m){
      int col = tid + 256*m;
      float z = (y[rr][m]-mean)*inv*g[col] + be[col];
      z = fmaxf(z, 0.f);
      int k = col >> 7, hh2 = col & 127;
      out[((t*cKN) + k*cN + nn)*cH + hh2] = z;
    }
  }
}

// round-12: preconvert the 4 LSTM weight matrices [128][512] into
// fragment-ordered split-bf16 arrays (per mat: 65536 hi + 65536 lo ushorts,
// layout ((n*4+s)*64+l)*8+e with k = 32s + 16(e>>2) + 4g + (e&3), col=16n+(l&15)).
// Output overlays the dead mhp_W region (1.31 MB >= 1 MB). One-time, ~10us.
__global__ __launch_bounds__(256) void k_wprep(const float* w0, const float* w1,
    const float* w2, const float* w3, unsigned short* out){
  int idx = blockIdx.x*256 + threadIdx.x;   // 32768 total
  int m = idx >> 13;
  int rest = idx & 8191;
  int n = rest >> 8;
  int s = (rest >> 6) & 3;
  int l = rest & 63;
  int g = l >> 4, c16 = l & 15;
  const float* W = (m==0) ? w0 : ((m==1) ? w1 : ((m==2) ? w2 : w3));
  unsigned short hi[8], lo[8];
  #pragma unroll
  for (int e = 0; e < 8; ++e){
    int k = 32*s + 16*(e>>2) + 4*g + (e&3);
    float v = W[k*512 + 16*n + c16];
    hi[e] = f2h(v); lo[e] = f2h(v - hif(v));
  }
  size_t base = (size_t)m*131072 + (size_t)((n*4 + s)*64 + l)*8;
  *(uint4*)&out[base]         = *(const uint4*)hi;
  *(uint4*)&out[base + 65536] = *(const uint4*)lo;
}

// round-13: MFMA LSTM, latency-hiding rework. R6 counters (122us, MfmaUtil 7.7,
// VGPR pinned at 128) indicate load-latency serialization: 64 weight-frag loads
// per step need ~1KB/lane to hoist; at the 128-VGPR occupancy target the
// compiler emits load->wait->mfma groups that each eat ~200cyc of L2 latency.
// Changes: (1) __launch_bounds__(512,2): we run 1 block/CU anyway (8 waves =
// 2/SIMD), so allow the full 256-VGPR budget; (2) explicit register
// double-buffer of the 16 (tt,s) weight groups; (3) x/soc global loads hoisted
// to the previous step's tail (issued after the gate update, consumed after the
// next barrier) so the barrier-protected region is LDS + MFMA only.
// L2-stream floor: 512KB/block/step at ~230GB/s per block ~= 26us/dispatch.
__global__ __launch_bounds__(512, 2) void k_lstm_mfma(const float* ge, float* outh,
    const float* hs0, const float* cn0, const float* soc,
    const unsigned short* wfA, const unsigned short* wfB,
    const float* bias, int phase){
  int r0 = blockIdx.x * 16;
  int tid = threadIdx.x;
  int w = tid >> 6, l = tid & 63;
  int g = l >> 4, c16 = l & 15;
  int scol = w*16 + c16;                 // state col owned by this lane
  __shared__ unsigned short HFh[4][64][8], HFl[4][64][8];   // 8 KB
  // producer slot constants: scol -> (s, gf, e); lane writes rows 4g+r
  int ps = scol >> 5, prem = scol & 31;
  int pgf = (prem >> 2) & 3;
  int pe  = ((prem >> 4) << 2) + (prem & 3);
  float c[4], h[4];
  #pragma unroll
  for (int r = 0; r < 4; ++r){
    int nn = (r0 + 4*g + r) & 127;
    c[r] = cn0[nn*cH + scol];
    h[r] = hs0[nn*cH + scol];
  }
  float bias_t[4];
  #pragma unroll
  for (int tt = 0; tt < 4; ++tt) bias_t[tt] = bias[tt*128 + scol];

  // prefetch x (and soc) for t=0
  f32x4 xr[8];
  float socr[4];
  {
    const f32x4* gp = (const f32x4*)ge + ((size_t)(r0 + c16))*32;
    #pragma unroll
    for (int s = 0; s < 4; ++s){ xr[2*s] = gp[8*s + g]; xr[2*s+1] = gp[8*s + 4 + g]; }
    if (phase == 2){
      #pragma unroll
      for (int r = 0; r < 4; ++r)
        socr[r] = soc[(size_t)(r0 + 4*g + r)*cH + scol];
    }
  }

  for (int t = 0; t < cT; ++t){
    if (phase == 2){
      #pragma unroll
      for (int r = 0; r < 4; ++r){
        c[r] += socr[r];
        h[r] += tanhf(c[r]);
      }
    }
    // h fragments to LDS + x conversion (no global latency in here)
    #pragma unroll
    for (int r = 0; r < 4; ++r){
      HFh[ps][pgf*16 + 4*g + r][pe] = f2h(h[r]);
      HFl[ps][pgf*16 + 4*g + r][pe] = f2h(h[r] - hif(h[r]));
    }
    bf16x8 xh[4], xl[4];
    #pragma unroll
    for (int s = 0; s < 4; ++s){
      union { unsigned short u[8]; bf16x8 v; } uh, ul;
      #pragma unroll
      for (int m2 = 0; m2 < 4; ++m2){
        float a0 = xr[2*s][m2], b0 = xr[2*s+1][m2];
        uh.u[m2]   = f2h(a0); ul.u[m2]   = f2h(a0 - hif(a0));
        uh.u[4+m2] = f2h(b0); ul.u[4+m2] = f2h(b0 - hif(b0));
      }
      xh[s] = uh.v; xl[s] = ul.v;
    }
    __syncthreads();                      // h fragment buffer complete
    bf16x8 hh[4], hl[4];
    #pragma unroll
    for (int s = 0; s < 4; ++s){
      hh[s] = *(const bf16x8*)&HFh[s][l][0];
      hl[s] = *(const bf16x8*)&HFl[s][l][0];
    }
    // 16 (tt,s) weight groups, register double-buffered
    f32x4 a4[4];
    #pragma unroll
    for (int tt = 0; tt < 4; ++tt){
      float bb = bias_t[tt];
      f32x4 acc = {bb, bb, bb, bb};
      a4[tt] = acc;
    }
    {
      bf16x8 cAh, cAl, cBh, cBl, nAh, nAl, nBh, nBl;
      {
        size_t fo = (size_t)((w*4 + 0)*64 + l)*8;
        cAh = *(const bf16x8*)&wfA[fo];
        cAl = *(const bf16x8*)&wfA[65536 + fo];
        cBh = *(const bf16x8*)&wfB[fo];
        cBl = *(const bf16x8*)&wfB[65536 + fo];
      }
      #pragma unroll
      for (int j = 0; j < 16; ++j){
        int tt = j >> 2, s = j & 3;
        if (j < 15){
          int j2 = j + 1;
          int n2 = w + 8*(j2 >> 2), s2 = j2 & 3;
          size_t fo = (size_t)((n2*4 + s2)*64 + l)*8;
          nAh = *(const bf16x8*)&wfA[fo];
          nAl = *(const bf16x8*)&wfA[65536 + fo];
          nBh = *(const bf16x8*)&wfB[fo];
          nBl = *(const bf16x8*)&wfB[65536 + fo];
        }
        f32x4 acc = a4[tt];
        acc = __builtin_amdgcn_mfma_f32_16x16x32_bf16(xl[s], cAh, acc, 0, 0, 0);
        acc = __builtin_amdgcn_mfma_f32_16x16x32_bf16(xh[s], cAl, acc, 0, 0, 0);
        acc = __builtin_amdgcn_mfma_f32_16x16x32_bf16(xh[s], cAh, acc, 0, 0, 0);
        acc = __builtin_amdgcn_mfma_f32_16x16x32_bf16(hl[s], cBh, acc, 0, 0, 0);
        acc = __builtin_amdgcn_mfma_f32_16x16x32_bf16(hh[s], cBl, acc, 0, 0, 0);
        acc = __builtin_amdgcn_mfma_f32_16x16x32_bf16(hh[s], cBh, acc, 0, 0, 0);
        a4[tt] = acc;
        cAh = nAh; cAl = nAl; cBh = nBh; cBl = nBl;
      }
    }
    // gates + state update + output store
    #pragma unroll
    for (int r = 0; r < 4; ++r){
      float ig = sigm(a4[0][r]), fg = sigm(a4[1][r]);
      float gg = tanhf(a4[2][r]), og = sigm(a4[3][r]);
      c[r] = fg*c[r] + ig*gg;
      h[r] = og*tanhf(c[r]);
      outh[(size_t)t*cKN*cH + (size_t)(r0 + 4*g + r)*cH + scol] = h[r];
    }
    // prefetch x/soc for t+1 (hidden under the epilogue + next barrier)
    if (t < cT-1){
      const f32x4* gp = (const f32x4*)ge + ((size_t)(t+1)*cKN + r0 + c16)*32;
      #pragma unroll
      for (int s = 0; s < 4; ++s){ xr[2*s] = gp[8*s + g]; xr[2*s+1] = gp[8*s + 4 + g]; }
      if (phase == 2){
        #pragma unroll
        for (int r = 0; r < 4; ++r)
          socr[r] = soc[(size_t)(t+1)*cKN*cH + (size_t)(r0 + 4*g + r)*cH + scol];
      }
    }
    __syncthreads();                      // all HF reads done before next write
  }
}

// loc & scale heads, wave-local: wave = (head, row-pair), shfl reductions, no trees.
__global__ __launch_bounds__(256) void k_heads(const float* x,
  const float* lW1, const float* lb1, const float* lg, const float* lbe, const float* lW2, const float* lb2v,
  const float* sW1, const float* sb1, const float* sg, const float* sbe, const float* sW2, const float* sb2v,
  void* outv, int q0, float* locsc, const float* maxv, const float* svp, const int* flagp){
  const int ROWS = 4;
  int r0 = blockIdx.x*ROWS;
  __shared__ float xs[ROWS][cH];
  int tid = threadIdx.x;
  if (tid < ROWS*32){
    int rr = tid>>5, u4 = tid&31;
    ((float4*)&xs[rr][0])[u4] = ((const float4*)x)[(size_t)(r0+rr)*32 + u4];
  }
  __syncthreads();
  int wv = tid >> 6, lane = tid & 63;
  int head = wv & 1;
  int ra = (wv >> 1)*2, rb = ra + 1;     // local rows
  const float* W1 = head ? sW1 : lW1;
  const float* b1 = head ? sb1 : lb1;
  const float* gv = head ? sg  : lg;
  const float* be = head ? sbe : lbe;
  const float* W2 = head ? sW2 : lW2;
  const float* b2 = head ? sb2v: lb2v;
  int j0 = lane, j1 = lane + 64;
  float a00 = b1[j0], a01 = b1[j1];
  float a10 = a00, a11 = a01;
  for (int i = 0; i < cH; ++i){
    float w0 = W1[i*cH + j0], w1 = W1[i*cH + j1];
    float xa = xs[ra][i], xb = xs[rb][i];
    a00 += xa*w0; a01 += xa*w1;
    a10 += xb*w0; a11 += xb*w1;
  }
  float s0 = a00 + a01, s1 = a10 + a11;
  #pragma unroll
  for (int off = 1; off < 64; off <<= 1){
    s0 += __shfl_xor(s0, off);
    s1 += __shfl_xor(s1, off);
  }
  float mean0 = s0*(1.f/128.f), mean1 = s1*(1.f/128.f);
  float d00 = a00-mean0, d01 = a01-mean0, d10 = a10-mean1, d11 = a11-mean1;
  float v0 = d00*d00 + d01*d01, v1 = d10*d10 + d11*d11;
  #pragma unroll
  for (int off = 1; off < 64; off <<= 1){
    v0 += __shfl_xor(v0, off);
    v1 += __shfl_xor(v1, off);
  }
  float inv0 = rsqrtf(v0*(1.f/128.f) + 1e-5f);
  float inv1 = rsqrtf(v1*(1.f/128.f) + 1e-5f);
  float g0 = gv[j0], g1 = gv[j1], be0 = be[j0], be1 = be[j1];
  float z00 = fmaxf(d00*inv0*g0 + be0, 0.f);
  float z01 = fmaxf(d01*inv0*g1 + be1, 0.f);
  float z10 = fmaxf(d10*inv1*g0 + be0, 0.f);
  float z11 = fmaxf(d11*inv1*g1 + be1, 0.f);
  float w2a0 = W2[j0*2+0], w2a1 = W2[j0*2+1];
  float w2b0 = W2[j1*2+0], w2b1 = W2[j1*2+1];
  float oa0 = z00*w2a0 + z01*w2b0;   // row ra, out 0
  float oa1 = z00*w2a1 + z01*w2b1;   // row ra, out 1
  float ob0 = z10*w2a0 + z11*w2b0;
  float ob1 = z10*w2a1 + z11*w2b1;
  #pragma unroll
  for (int off = 1; off < 64; off <<= 1){
    oa0 += __shfl_xor(oa0, off);
    oa1 += __shfl_xor(oa1, off);
    ob0 += __shfl_xor(ob0, off);
    ob1 += __shfl_xor(ob1, off);
  }
  if (lane == 0){
    int flag = *flagp;
    float bias0 = b2[0], bias1 = b2[1];
    float ro[2][2] = {{oa0 + bias0, oa1 + bias1},{ob0 + bias0, ob1 + bias1}};
    int lr[2] = {ra, rb};
    for (int e = 0; e < 2; ++e){
      int rg = r0 + lr[e];
      int t = rg / cKN, rem = rg - t*cKN;
      int k = rem >> 7, nn = rem & 127;
      float u0 = ro[e][0], u1 = ro[e][1];
      if (head == 0){
        size_t oi = (((size_t)q0*cK + k)*cN + nn)*(cT*2) + t*2;
        if (flag){ ((bf16_t*)outv)[oi] = __float2bfloat16(u0); ((bf16_t*)outv)[oi+1] = __float2bfloat16(u1); }
        else     { ((float*)outv)[oi] = u0; ((float*)outv)[oi+1] = u1; }
        if (locsc){
          locsc[((size_t)t*cKN + rem)*2 + 0] = u0*maxv[nn*2+0] + svp[nn*2+0];
          locsc[((size_t)t*cKN + rem)*2 + 1] = u1*maxv[nn*2+1] + svp[nn*2+1];
        }
      } else {
        float e0 = (u0 > 0.f ? u0 : expm1f(u0)) + 1.001f;
        float e1 = (u1 > 0.f ? u1 : expm1f(u1)) + 1.001f;
        size_t oi = (((size_t)(q0+1)*cK + k)*cN + nn)*(cT*2) + t*2;
        if (flag){ ((bf16_t*)outv)[oi] = __float2bfloat16(e0); ((bf16_t*)outv)[oi+1] = __float2bfloat16(e1); }
        else     { ((float*)outv)[oi] = e0; ((float*)outv)[oi+1] = e1; }
      }
    }
  }
}

__global__ __launch_bounds__(256) void k_mask(const float* locsc, unsigned char* m){
  int st = blockIdx.x;
  int s = st / cT, t = st - s*cT;
  __shared__ float lx[cK][cNS], ly[cK][cNS];
  int tid = threadIdx.x;
  for (int p = tid; p < cK*cNS; p += 256){
    int k = p >> 5, i = p & 31;
    int row = t*cKN + k*cN + s*cNS + i;
    lx[k][i] = locsc[row*2+0];
    ly[k][i] = locsc[row*2+1];
  }
  __syncthreads();
  for (int p = tid; p < 1024; p += 256){
    int i = p >> 5, j = p & 31;
    bool any = false;
    for (int k = 0; k < cK; ++k){
      float dx = fabsf(lx[k][i]-lx[k][j]);
      float dy = fabsf(ly[k][i]-ly[k][j]);
      any = any || ((dx < 10.f) && (dy < 10.f));
    }
    m[st*1024 + p] = any ? 1 : 0;
  }
}

// QKV projection, 16 rows/block, weight reuse for 8 rows/thread
__global__ __launch_bounds__(256) void k_qkv(const float* x,
  const float* Wq, const float* bq, const float* Wk, const float* bk,
  const float* Wv, const float* bv,
  float* Q, float* K2, float* V){
  const int ROWS = 16;
  int r0 = blockIdx.x*ROWS;
  __shared__ float xs[ROWS][cH];
  int tid = threadIdx.x;
  for (int p = tid; p < ROWS*32; p += 256){
    int rr = p>>5, u4 = p&31;
    ((float4*)&xs[rr][0])[u4] = ((const float4*)x)[(size_t)(r0+rr)*32 + u4];
  }
  __syncthreads();
  int cl = tid & 127, half = tid >> 7;
  float aq[8], ak[8], av[8];
  float bq0 = bq[cl], bk0 = bk[cl], bv0 = bv[cl];
  #pragma unroll
  for (int r = 0; r < 8; ++r){ aq[r] = bq0; ak[r] = bk0; av[r] = bv0; }
  for (int i = 0; i < cH; ++i){
    float wq = Wq[i*cH+cl], wk = Wk[i*cH+cl], wv = Wv[i*cH+cl];
    #pragma unroll
    for (int q2 = 0; q2 < 8; ++q2){
      float xi = xs[half + 2*q2][i];
      aq[q2] += xi*wq; ak[q2] += xi*wk; av[q2] += xi*wv;
    }
  }
  #pragma unroll
  for (int q2 = 0; q2 < 8; ++q2){
    size_t gi = (size_t)(r0 + half + 2*q2)*cH + cl;
    Q[gi] = aq[q2]; K2[gi] = ak[q2]; V[gi] = av[q2];
  }
}

// round-10: MFMA attention (validated). Split-bf16 3-mfma products; QK^T =
// mfma(A=K, B=Q) with k-map k=16(e>>2)+4g+(e&3); PV A-frag = lane's own
// S-accumulator. No-max softmax. K/V staged to LDS in fragment order.
__global__ __launch_bounds__(256) void k_attn(const float* Q, const float* Kx, const float* V,
                       const unsigned char* msk, float* ctx){
  int qs   = blockIdx.x;        // 0..4 : group of 8 q-tiles (2 per wave)
  int head = blockIdx.y;        // 0..3
  int st   = blockIdx.z;        // s*cT + t
  int s = st / cT, t = st - s*cT;
  __shared__ unsigned short KLh[2][1024], KLl[2][1024], VLh[2][1024], VLl[2][1024]; // 16 KB
  int tid = threadIdx.x;
  int w = tid >> 6, lane = tid & 63;
  int g = lane >> 4, col = lane & 15;
  const float scl = 0.17677669529663687f;   // 1/sqrt(32)

  // mask rows (q_agent = col, col+16) packed to 32-bit words (byte->bit)
  unsigned int mw0 = 0, mw1 = 0;
  {
    const unsigned int* mr0 = (const unsigned int*)(msk + st*1024 + col*32);
    const unsigned int* mr1 = (const unsigned int*)(msk + st*1024 + (16+col)*32);
    #pragma unroll
    for (int j2 = 0; j2 < 8; ++j2){
      mw0 |= (((mr0[j2] * 0x01020408u) >> 24) & 0xFu) << (4*j2);
      mw1 |= (((mr1[j2] * 0x01020408u) >> 24) & 0xFu) << (4*j2);
    }
  }

  // Q fragments (pre-scaled by scl), 2 tiles per wave; B col = lane&15
  bf16x8 Qh[2], Ql[2];
  int modes[2], ahs[2];
  #pragma unroll
  for (int i = 0; i < 2; ++i){
    int tt = qs*8 + 4*i + w;       // 0..39
    int mode = tt >> 1, ah = tt & 1;
    modes[i] = mode; ahs[i] = ah;
    int qrow = t*cKN + mode*cN + s*cNS + ah*16 + col;
    const f32x4* qp = (const f32x4*)Q + (size_t)qrow*32 + head*8;
    f32x4 qa = qp[g], qb = qp[4+g];     // dims 4g..4g+3, 16+4g..16+4g+3
    union { unsigned short u[8]; bf16x8 v; } uh, ul;
    #pragma unroll
    for (int m = 0; m < 4; ++m){
      float x0 = qa[m]*scl;
      uh.u[m] = f2h(x0);
      ul.u[m] = f2h(x0 - hif(x0));
      float x1 = qb[m]*scl;
      uh.u[4+m] = f2h(x1);
      ul.u[4+m] = f2h(x1 - hif(x1));
    }
    Qh[i] = uh.v; Ql[i] = ul.v;
  }

  // staging indices
  int kk = tid >> 3, f4 = tid & 7;                 // K: key kk, dims 4*f4..+3
  int kwi = (((kk>>4)*4 + (f4&3))*16 + (kk&15))*8 + (f4>>2)*4;
  int vd = tid & 31, quad = tid >> 5;              // V: dim vd, keys base..+3
  int vkey = (quad>>2)*16 + (quad&3)*4;
  int vwi = (((vd>>4)*4 + (quad&3))*16 + (vd&15))*8 + (quad>>2)*4;

  const size_t cstepK = (size_t)cN*32;             // float4 per chunk (one mode)
  const size_t cstepV = (size_t)cN*128;            // float per chunk
  const float4* kptr = (const float4*)Kx + ((size_t)(t*cKN + s*cNS + kk))*32 + head*8 + f4;
  const float*  vptr = V + ((size_t)(t*cKN + s*cNS + vkey))*128 + head*32 + vd;

  float4 kv; float vm0, vm1, vm2, vm3;
  kv = *kptr; kptr += cstepK;
  vm0 = vptr[0]; vm1 = vptr[128]; vm2 = vptr[256]; vm3 = vptr[384]; vptr += cstepV;
  {
    unsigned int h0 = (unsigned int)f2h(kv.x) | ((unsigned int)f2h(kv.y)<<16);
    unsigned int h1 = (unsigned int)f2h(kv.z) | ((unsigned int)f2h(kv.w)<<16);
    float r0 = kv.x-hif(kv.x), r1 = kv.y-hif(kv.y), r2 = kv.z-hif(kv.z), r3 = kv.w-hif(kv.w);
    unsigned int l0 = (unsigned int)f2h(r0) | ((unsigned int)f2h(r1)<<16);
    unsigned int l1 = (unsigned int)f2h(r2) | ((unsigned int)f2h(r3)<<16);
    *(uint2*)&KLh[0][kwi] = make_uint2(h0,h1);
    *(uint2*)&KLl[0][kwi] = make_uint2(l0,l1);
    unsigned int vh0 = (unsigned int)f2h(vm0) | ((unsigned int)f2h(vm1)<<16);
    unsigned int vh1 = (unsigned int)f2h(vm2) | ((unsigned int)f2h(vm3)<<16);
    float s0 = vm0-hif(vm0), s1 = vm1-hif(vm1), s2 = vm2-hif(vm2), s3 = vm3-hif(vm3);
    unsigned int vl0 = (unsigned int)f2h(s0) | ((unsigned int)f2h(s1)<<16);
    unsigned int vl1 = (unsigned int)f2h(s2) | ((unsigned int)f2h(s3)<<16);
    *(uint2*)&VLh[0][vwi] = make_uint2(vh0,vh1);
    *(uint2*)&VLl[0][vwi] = make_uint2(vl0,vl1);
  }
  __syncthreads();

  const f32x4 Z = {0.f, 0.f, 0.f, 0.f};
  f32x4 O[2][2] = {{Z, Z}, {Z, Z}};
  float lac[2] = {0.f, 0.f};

  for (int ch = 0; ch < 20; ++ch){
    int par = ch & 1;
    if (ch < 19){
      kv = *kptr; kptr += cstepK;
      vm0 = vptr[0]; vm1 = vptr[128]; vm2 = vptr[256]; vm3 = vptr[384]; vptr += cstepV;
    }
    // fragment reads (shared across this wave's tiles)
    bf16x8 KAh0 = *(const bf16x8*)&KLh[par][( g      *16 + col)*8];
    bf16x8 KAl0 = *(const bf16x8*)&KLl[par][( g      *16 + col)*8];
    bf16x8 KAh1 = *(const bf16x8*)&KLh[par][((4 + g) *16 + col)*8];
    bf16x8 KAl1 = *(const bf16x8*)&KLl[par][((4 + g) *16 + col)*8];
    bf16x8 VBh0 = *(const bf16x8*)&VLh[par][( g      *16 + col)*8];
    bf16x8 VBl0 = *(const bf16x8*)&VLl[par][( g      *16 + col)*8];
    bf16x8 VBh1 = *(const bf16x8*)&VLh[par][((4 + g) *16 + col)*8];
    bf16x8 VBl1 = *(const bf16x8*)&VLl[par][((4 + g) *16 + col)*8];
    #pragma unroll
    for (int i = 0; i < 2; ++i){
      f32x4 sa = Z, sb = Z;
      sa = __builtin_amdgcn_mfma_f32_16x16x32_bf16(KAl0, Qh[i], sa, 0, 0, 0);
      sa = __builtin_amdgcn_mfma_f32_16x16x32_bf16(KAh0, Ql[i], sa, 0, 0, 0);
      sa = __builtin_amdgcn_mfma_f32_16x16x32_bf16(KAh0, Qh[i], sa, 0, 0, 0);
      sb = __builtin_amdgcn_mfma_f32_16x16x32_bf16(KAl1, Qh[i], sb, 0, 0, 0);
      sb = __builtin_amdgcn_mfma_f32_16x16x32_bf16(KAh1, Ql[i], sb, 0, 0, 0);
      sb = __builtin_amdgcn_mfma_f32_16x16x32_bf16(KAh1, Qh[i], sb, 0, 0, 0);
      unsigned int mw = ahs[i] ? mw1 : mw0;
      float p[8];
      #pragma unroll
      for (int r = 0; r < 4; ++r){
        float e0 = __expf(sa[r]);
        float e1 = __expf(sb[r]);
        p[r]   = ((mw >> (4*g + r)) & 1)        ? e0 : 0.f;
        p[4+r] = ((mw >> (16 + 4*g + r)) & 1)   ? e1 : 0.f;
      }
      lac[i] += ((p[0]+p[1])+(p[2]+p[3])) + ((p[4]+p[5])+(p[6]+p[7]));
      union { unsigned short u[8]; bf16x8 v; } Ph, Pl;
      #pragma unroll
      for (int e = 0; e < 8; ++e){
        Ph.u[e] = f2h(p[e]);
        Pl.u[e] = f2h(p[e] - hif(p[e]));
      }
      O[i][0] = __builtin_amdgcn_mfma_f32_16x16x32_bf16(Pl.v, VBh0, O[i][0], 0, 0, 0);
      O[i][0] = __builtin_amdgcn_mfma_f32_16x16x32_bf16(Ph.v, VBl0, O[i][0], 0, 0, 0);
      O[i][0] = __builtin_amdgcn_mfma_f32_16x16x32_bf16(Ph.v, VBh0, O[i][0], 0, 0, 0);
      O[i][1] = __builtin_amdgcn_mfma_f32_16x16x32_bf16(Pl.v, VBh1, O[i][1], 0, 0, 0);
      O[i][1] = __builtin_amdgcn_mfma_f32_16x16x32_bf16(Ph.v, VBl1, O[i][1], 0, 0, 0);
      O[i][1] = __builtin_amdgcn_mfma_f32_16x16x32_bf16(Ph.v, VBh1, O[i][1], 0, 0, 0);
    }
    __syncthreads();   // all frag reads of [par] done
    if (ch < 19){
      int nb = 1 - par;
      unsigned int h0 = (unsigned int)f2h(kv.x) | ((unsigned int)f2h(kv.y)<<16);
      unsigned int h1 = (unsigned int)f2h(kv.z) | ((unsigned int)f2h(kv.w)<<16);
      float r0 = kv.x-hif(kv.x), r1 = kv.y-hif(kv.y), r2 = kv.z-hif(kv.z), r3 = kv.w-hif(kv.w);
      unsigned int l0 = (unsigned int)f2h(r0) | ((unsigned int)f2h(r1)<<16);
      unsigned int l1 = (unsigned int)f2h(r2) | ((unsigned int)f2h(r3)<<16);
      *(uint2*)&KLh[nb][kwi] = make_uint2(h0,h1);
      *(uint2*)&KLl[nb][kwi] = make_uint2(l0,l1);
      unsigned int vh0 = (unsigned int)f2h(vm0) | ((unsigned int)f2h(vm1)<<16);
      unsigned int vh1 = (unsigned int)f2h(vm2) | ((unsigned int)f2h(vm3)<<16);
      float s0 = vm0-hif(vm0), s1 = vm1-hif(vm1), s2 = vm2-hif(vm2), s3 = vm3-hif(vm3);
      unsigned int vl0 = (unsigned int)f2h(s0) | ((unsigned int)f2h(s1)<<16);
      unsigned int vl1 = (unsigned int)f2h(s2) | ((unsigned int)f2h(s3)<<16);
      *(uint2*)&VLh[nb][vwi] = make_uint2(vh0,vh1);
      *(uint2*)&VLl[nb][vwi] = make_uint2(vl0,vl1);
    }
    __syncthreads();   // next buffer visible
  }

  // epilogue: row denominators + normalized writes
  #pragma unroll
  for (int i = 0; i < 2; ++i){
    float lsum = lac[i];
    lsum += __shfl_xor(lsum, 16);
    lsum += __shfl_xor(lsum, 32);
    int base = t*cKN + modes[i]*cN + s*cNS + ahs[i]*16;
    #pragma unroll
    for (int r = 0; r < 4; ++r){
      float lq = __shfl(lsum, 4*g + r);
      float rinv = 1.f / lq;
      float* cp = ctx + (size_t)(base + 4*g + r)*cH + head*cHD;
      cp[col]      = O[i][0][r] * rinv;
      cp[col+16]   = O[i][1][r] * rinv;
    }
  }
}

// Wo1 + relu, 8 rows/block, weight reuse
__global__ __launch_bounds__(256) void k_wo1(const float* x, const float* W, const float* b, float* o){
  const int ROWS = 8;
  int r0 = blockIdx.x*ROWS;
  __shared__ float xs[ROWS][cH];
  int tid = threadIdx.x;
  {
    int rr = tid>>5, u4 = tid&31;
    ((float4*)&xs[rr][0])[u4] = ((const float4*)x)[(size_t)(r0+rr)*32 + u4];
  }
  __syncthreads();
  float a[8];
  float bb = b[tid];
  #pragma unroll
  for (int r = 0; r < 8; ++r) a[r] = bb;
  for (int i = 0; i < cH; ++i){
    float w = W[i*256 + tid];
    #pragma unroll
    for (int r = 0; r < 8; ++r) a[r] += xs[r][i]*w;
  }
  #pragma unroll
  for (int r = 0; r < 8; ++r) o[(size_t)(r0+r)*256 + tid] = fmaxf(a[r], 0.f);
}

// Wo2, 16 rows/block, weight reuse
__global__ __launch_bounds__(256) void k_wo2(const float* x, const float* W, const float* b, float* o){
  const int ROWS = 16;
  int r0 = blockIdx.x*ROWS;
  __shared__ float xs[ROWS][256];
  int tid = threadIdx.x;
  for (int p = tid; p < ROWS*64; p += 256){
    int rr = p>>6, u4 = p&63;
    ((float4*)&xs[rr][0])[u4] = ((const float4*)x)[(size_t)(r0+rr)*64 + u4];
  }
  __syncthreads();
  int cl = tid & 127, half = tid >> 7;
  float a[8];
  float bb = b[cl];
  #pragma unroll
  for (int r = 0; r < 8; ++r) a[r] = bb;
  for (int i = 0; i < 256; ++i){
    float w = W[i*cH + cl];
    #pragma unroll
    for (int q2 = 0; q2 < 8; ++q2) a[q2] += xs[half + 2*q2][i]*w;
  }
  #pragma unroll
  for (int q2 = 0; q2 < 8; ++q2) o[(size_t)(r0 + half + 2*q2)*cH + cl] = a[q2];
}

extern "C" void kernel_launch(void* const* d_in, const int* in_sizes, int n_in,
                              void* d_out, int out_size, void* d_ws, size_t ws_size,
                              hipStream_t stream){
  (void)in_sizes; (void)n_in; (void)out_size; (void)ws_size;

  int*   flagp = (int*)d_ws;
  float* conv  = (float*)d_ws + 64;
  float* big   = (float*)d_ws + 978112;

  const float* ge_f   = conv + 0;
  const float* hs_f   = conv + 196608;
  const float* cn_f   = conv + 212992;
  const float* sv_f   = conv + 229376;
  const float* mx_f   = conv + 229632;
  const float* mhpW_f = conv + 229888;
  const float* mhpb_f = conv + 557568;
  const float* mhpg_f = conv + 560128;
  const float* mhpbe_f= conv + 562688;
  const float* l1Wih_f= conv + 565248;
  const float* l1Whh_f= conv + 630784;
  const float* l1b_f  = conv + 696320;
  const float* l2Wih_f= conv + 696832;
  const float* l2Whh_f= conv + 762368;
  const float* l2b_f  = conv + 827904;
  const float* Wq_f   = conv + 828416;
  const float* bq_f   = conv + 844800;
  const float* Wk_f   = conv + 844928;
  const float* bk_f   = conv + 861312;
  const float* Wv_f   = conv + 861440;
  const float* bv_f   = conv + 877824;
  const float* Wo1_f  = conv + 877952;
  const float* bo1_f  = conv + 910720;
  const float* Wo2_f  = conv + 910976;
  const float* bo2_f  = conv + 943744;
  const float* locW1_f= conv + 943872;
  const float* locb1_f= conv + 960256;
  const float* locg_f = conv + 960384;
  const float* locbe_f= conv + 960512;
  const float* locW2_f= conv + 960640;
  const float* locb2_f= conv + 960896;
  const float* sclW1_f= conv + 960960;
  const float* sclb1_f= conv + 977344;
  const float* sclg_f = conv + 977472;
  const float* sclbe_f= conv + 977600;
  const float* sclW2_f= conv + 977728;
  const float* sclb2_f= conv + 977984;

  const size_t SLOT = (size_t)cT*cKN*cH;
  float* geb = big;
  float* o1b = big + SLOT;
  float* Qb  = big + 2*SLOT;
  float* Kb  = big + 3*SLOT;
  float* Vb  = big + 4*SLOT;
  float* locsc = big + 5*SLOT;
  unsigned char* maskb = (unsigned char*)(locsc + (size_t)cT*cKN*2);
  float* t1 = Qb;        // spans slots 2-3 (Q/K dead after attn)
  float* social = Vb;    // overlays V after attention

  // LSTM weight fragments overlay the mhp_W region (1.31 MB, dead after k_mhp)
  unsigned short* wfrag = (unsigned short*)(conv + 229888);

  Ptrs ptrs;
  for (int i = 0; i < 37; ++i) ptrs.p[i] = d_in[i];

  k_detect<<<1, 64, 0, stream>>>((const unsigned short*)d_in[0], flagp, (unsigned int*)d_out);
  k_convert<<<(CONV_TOTAL+255)/256, 256, 0, stream>>>(ptrs, flagp, conv);
  k_mhp<<<cT*cN/2, 256, 0, stream>>>(ge_f, mhpW_f, mhpb_f, mhpg_f, mhpbe_f, geb);
  k_wprep<<<128, 256, 0, stream>>>(l1Wih_f, l1Whh_f, l2Wih_f, l2Whh_f, wfrag);
  k_lstm_mfma<<<160, 512, 0, stream>>>(geb, o1b, hs_f, cn_f, (const float*)0,
                                       wfrag + 0, wfrag + 131072, l1b_f, 1);
  k_heads<<<cT*cKN/4, 256, 0, stream>>>(o1b, locW1_f,locb1_f,locg_f,locbe_f,locW2_f,locb2_f,
                                        sclW1_f,sclb1_f,sclg_f,sclbe_f,sclW2_f,sclb2_f,
                                        d_out, 0, locsc, mx_f, sv_f, flagp);
  k_mask<<<cS*cT, 256, 0, stream>>>(locsc, maskb);
  k_qkv<<<cT*cKN/16, 256, 0, stream>>>(o1b, Wq_f,bq_f, Wk_f,bk_f, Wv_f,bv_f, Qb, Kb, Vb);
  {
    dim3 ag(5, 4, cS*cT);
    k_attn<<<ag, 256, 0, stream>>>(Qb, Kb, Vb, maskb, o1b);   // ctx overlays out1
  }
  k_wo1<<<cT*cKN/8, 256, 0, stream>>>(o1b, Wo1_f, bo1_f, t1);
  k_wo2<<<cT*cKN/16, 256, 0, stream>>>(t1, Wo2_f, bo2_f, social);
  k_lstm_mfma<<<160, 512, 0, stream>>>(geb, o1b, hs_f, cn_f, social,
                                       wfrag + 262144, wfrag + 393216, l2b_f, 2);
  k_heads<<<cT*cKN/4, 256, 0, stream>>>(o1b, locW1_f,locb1_f,locg_f,locbe_f,locW2_f,locb2_f,
                                        sclW1_f,sclb1_f,sclg_f,sclbe_f,sclW2_f,sclb2_f,
                                        d_out, 2, (float*)0, mx_f, sv_f, flagp);
}